// Round 1
// baseline (978.088 us; speedup 1.0000x reference)
//
#include <hip/hip_runtime.h>
#include <hip/hip_bf16.h>

// DeepSeekMoE: B=4,S=2048,D=1024,H=1024,E=7,NS=1,topk=3. N=8192 tokens.
#define N_TOK 8192
#define DIM   1024
#define HID   1024
#define NE    7
#define BM    128
#define BN    128
#define BK    32
#define MT_ROUTED 199            // max Σ ceil(Ne/128) = 198, +1 slack
#define PAIR_CAP (MT_ROUTED*128) // 25472 padded pair rows

typedef __attribute__((ext_vector_type(8))) short bf16x8;
typedef __attribute__((ext_vector_type(4))) float f32x4;

typedef __attribute__((address_space(3))) ushort lds_us_t;
typedef __attribute__((address_space(1))) const ushort glb_us_t;

__device__ __forceinline__ void gll16(const ushort* g, ushort* l) {
    // async global->LDS, 16B per lane; LDS dest is wave-uniform base + lane*16
    __builtin_amdgcn_global_load_lds((glb_us_t*)g, (lds_us_t*)l, 16, 0, 0);
}

__device__ __forceinline__ unsigned short f2bf(float f) {
    unsigned int u = __builtin_bit_cast(unsigned int, f);
    u += 0x7fffu + ((u >> 16) & 1u);   // RNE
    return (unsigned short)(u >> 16);
}

__device__ __forceinline__ float siluf(float v) { return v / (1.f + __expf(-v)); }

// ---------------- gate: logits -> softmax -> top3 -> renorm weights ----------
__global__ void gate_kernel(const float* __restrict__ x, const float* __restrict__ gw,
                            const float* __restrict__ gb, const float* __restrict__ bia,
                            int* __restrict__ topk_e, float* __restrict__ topk_w,
                            int* __restrict__ counts)
{
    const int lane = threadIdx.x & 63, wid = threadIdx.x >> 6;
    const int n = blockIdx.x * 4 + wid;
    const float* xr = x + (size_t)n * DIM;
    float p[NE];
#pragma unroll
    for (int e = 0; e < NE; e++) p[e] = 0.f;
    for (int i = 0; i < DIM / 64; i++) {
        int idx = i * 64 + lane;
        float xv = xr[idx];
        const float* g = gw + idx * NE;
#pragma unroll
        for (int e = 0; e < NE; e++) p[e] += xv * g[e];
    }
#pragma unroll
    for (int e = 0; e < NE; e++)
        for (int off = 32; off; off >>= 1) p[e] += __shfl_xor(p[e], off);
    if (lane == 0) {
        float l[NE], m = -1e30f;
#pragma unroll
        for (int e = 0; e < NE; e++) { l[e] = p[e] + gb[e]; m = fmaxf(m, l[e]); }
        float s = 0.f;
#pragma unroll
        for (int e = 0; e < NE; e++) { l[e] = __expf(l[e] - m); s += l[e]; }
        float inv = 1.f / s;
#pragma unroll
        for (int e = 0; e < NE; e++) l[e] *= inv;          // probs
        float adj[NE]; bool used[NE];
#pragma unroll
        for (int e = 0; e < NE; e++) { adj[e] = l[e] + bia[e]; used[e] = false; }
        int sel[3]; float w[3]; float ws = 0.f;
        for (int k = 0; k < 3; k++) {
            int b = -1; float bv = -1e30f;
            for (int e = 0; e < NE; e++)
                if (!used[e] && adj[e] > bv) { bv = adj[e]; b = e; }
            used[b] = true; sel[k] = b; w[k] = l[b]; ws += w[k];
        }
        float iws = 1.f / ws;
        for (int k = 0; k < 3; k++) {
            topk_e[n * 3 + k] = sel[k];
            topk_w[n * 3 + k] = w[k] * iws;
            atomicAdd(&counts[sel[k]], 1);
        }
    }
}

// --------- setup (1 thread): scan counts, tile list, cursors, pad slots ------
__global__ void setup_kernel(int* __restrict__ ctrl, int* __restrict__ row_tok,
                             float* __restrict__ row_w)
{
    if (threadIdx.x != 0 || blockIdx.x != 0) return;
    int* counts = ctrl + 8; int* cursors = ctrl + 16; int* tiles = ctrl + 32;
    int nm = 0, off = 0;
    for (int e = 0; e < NE; e++) {
        int c = counts[e];
        int padc = (c + 127) & ~127;
        cursors[e] = off;
        for (int t = 0; t < padc; t += 128) { tiles[nm * 2] = e; tiles[nm * 2 + 1] = off + t; nm++; }
        for (int i = c; i < padc; i++) { row_tok[off + i] = 0; row_w[off + i] = 0.f; }
        off += padc;
    }
    ctrl[0] = nm;
}

// --------- scatter: token -> per-expert padded row slots ---------------------
__global__ void scatter_kernel(const int* __restrict__ topk_e, const float* __restrict__ topk_w,
                               int* __restrict__ ctrl, int* __restrict__ row_tok,
                               float* __restrict__ row_w)
{
    int n = blockIdx.x * blockDim.x + threadIdx.x;
    if (n >= N_TOK) return;
    int* cursors = ctrl + 16;
    for (int k = 0; k < 3; k++) {
        int e = topk_e[n * 3 + k];
        int slot = atomicAdd(&cursors[e], 1);
        row_tok[slot] = n;
        row_w[slot] = topk_w[n * 3 + k];
    }
}

// --------- fp32 -> bf16 straight convert (x) ---------------------------------
__global__ void convert_x(const float* __restrict__ x, ushort* __restrict__ xb)
{
    int i = blockIdx.x * blockDim.x + threadIdx.x;   // 4 floats per thread
    float4 v = ((const float4*)x)[i];
    ushort4 o;
    o.x = f2bf(v.x); o.y = f2bf(v.y); o.z = f2bf(v.z); o.w = f2bf(v.w);
    ((ushort4*)xb)[i] = o;
}

// --------- transpose+convert all 1024x1024 weight matrices to B^T bf16 -------
__global__ void transpose_convert(const float* __restrict__ w1, const float* __restrict__ wg,
                                  const float* __restrict__ w2, const float* __restrict__ sw1,
                                  const float* __restrict__ sw2,
                                  ushort* __restrict__ w1T, ushort* __restrict__ wgT,
                                  ushort* __restrict__ w2T, ushort* __restrict__ sw1T,
                                  ushort* __restrict__ sw2T)
{
    int z = blockIdx.z;
    const float* src; ushort* dst;
    if (z < 7)       { src = w1 + (size_t)z * (DIM*HID);        dst = w1T + (size_t)z * (DIM*HID); }
    else if (z < 14) { src = wg + (size_t)(z - 7) * (DIM*HID);  dst = wgT + (size_t)(z - 7) * (DIM*HID); }
    else if (z < 21) { src = w2 + (size_t)(z - 14) * (DIM*HID); dst = w2T + (size_t)(z - 14) * (DIM*HID); }
    else if (z == 21){ src = sw1; dst = sw1T; }
    else             { src = sw2; dst = sw2T; }
    __shared__ float t[32][33];
    int bx = blockIdx.x * 32, by = blockIdx.y * 32;
    int lx = threadIdx.x & 31, ly = threadIdx.x >> 5;   // 8 rows per pass
#pragma unroll
    for (int i = 0; i < 32; i += 8)
        t[ly + i][lx] = src[(size_t)(by + ly + i) * 1024 + bx + lx];
    __syncthreads();
#pragma unroll
    for (int i = 0; i < 32; i += 8) {
        int r = ly + i;
        dst[(size_t)(bx + r) * 1024 + by + lx] = f2bf(t[lx][r]);
    }
}

// --------- GEMM1: h = act(x @ W) ; GATED: silu(x@w1)*(x@wg); else silu(+bias) -
// A [rows][1024] bf16 row-major; B^T [1024][1024] bf16 per expert.
template<int GATHER, int GATED, int BIAS>
__global__ void __launch_bounds__(256, GATED ? 1 : 2)
gemm1_kernel(const ushort* __restrict__ A, const ushort* __restrict__ B1,
             const ushort* __restrict__ B2, const float* __restrict__ bias,
             ushort* __restrict__ Hout, const int* __restrict__ row_tok,
             const int* __restrict__ ctrl)
{
    __shared__ ushort As[BM * BK];
    __shared__ ushort Bs1[BN * BK];
    __shared__ ushort Bs2[BN * BK];

    const int tid = threadIdx.x;
    const int lane = tid & 63, wid = tid >> 6;
    const int wr = wid >> 1, wc = wid & 1;

    int e = 0, prow0;
    if (GATHER) {
        if ((int)blockIdx.x >= ctrl[0]) return;
        e     = ctrl[32 + 2 * blockIdx.x];
        prow0 = ctrl[32 + 2 * blockIdx.x + 1];
    } else {
        prow0 = blockIdx.x * BM;
    }
    const int col0 = blockIdx.y * BN;

    const ushort* B1e = B1 + (size_t)e * (DIM * HID);
    const ushort* B2e = B2 + (size_t)e * (DIM * HID);

    const ushort *ag[2], *b1g[2], *b2g[2];
    int ldso[2];
#pragma unroll
    for (int p = 0; p < 2; p++) {
        int chunk = wid * 2 + p;
        int rit = chunk * 16 + (lane >> 2);
        int kc = (lane & 3) * 8;
        int ar = GATHER ? row_tok[prow0 + rit] : (prow0 + rit);
        ag[p]  = A + (size_t)ar * DIM + kc;
        b1g[p] = B1e + (size_t)(col0 + rit) * DIM + kc;
        b2g[p] = B2e + (size_t)(col0 + rit) * DIM + kc;
        ldso[p] = chunk * 512;   // ushort units: 1KB chunks
    }

    f32x4 zero4 = {0.f, 0.f, 0.f, 0.f};
    f32x4 acc1[4][4], acc2[4][4];
#pragma unroll
    for (int i = 0; i < 4; i++)
#pragma unroll
        for (int j = 0; j < 4; j++) { acc1[i][j] = zero4; acc2[i][j] = zero4; }

    const int lrow = lane & 15;
    const int koff = (lane >> 4) * 8;

    for (int kt = 0; kt < DIM; kt += BK) {
#pragma unroll
        for (int p = 0; p < 2; p++) {
            gll16(ag[p] + kt, As + ldso[p]);
            gll16(b1g[p] + kt, Bs1 + ldso[p]);
            if (GATED) gll16(b2g[p] + kt, Bs2 + ldso[p]);
        }
        __syncthreads();
        bf16x8 af[4], bf1[4], bf2[4];
#pragma unroll
        for (int i = 0; i < 4; i++)
            af[i] = *(const bf16x8*)(As + (wr * 64 + i * 16 + lrow) * BK + koff);
#pragma unroll
        for (int j = 0; j < 4; j++) {
            bf1[j] = *(const bf16x8*)(Bs1 + (wc * 64 + j * 16 + lrow) * BK + koff);
            if (GATED) bf2[j] = *(const bf16x8*)(Bs2 + (wc * 64 + j * 16 + lrow) * BK + koff);
        }
#pragma unroll
        for (int i = 0; i < 4; i++)
#pragma unroll
            for (int j = 0; j < 4; j++) {
                acc1[i][j] = __builtin_amdgcn_mfma_f32_16x16x32_bf16(af[i], bf1[j], acc1[i][j], 0, 0, 0);
                if (GATED)
                    acc2[i][j] = __builtin_amdgcn_mfma_f32_16x16x32_bf16(af[i], bf2[j], acc2[i][j], 0, 0, 0);
            }
        __syncthreads();
    }

#pragma unroll
    for (int i = 0; i < 4; i++)
#pragma unroll
        for (int j = 0; j < 4; j++)
#pragma unroll
            for (int r = 0; r < 4; r++) {
                int row = prow0 + wr * 64 + i * 16 + (lane >> 4) * 4 + r;
                int col = col0 + wc * 64 + j * 16 + (lane & 15);
                float v = acc1[i][j][r];
                float h;
                if (GATED) h = siluf(v) * acc2[i][j][r];
                else { if (BIAS) v += bias[col]; h = siluf(v); }
                Hout[(size_t)row * HID + col] = f2bf(h);
            }
}

// --------- GEMM2: y = h @ W2 ; ROUTED: atomicAdd(w*y) ; else store y+bias -----
template<int ROUTED>
__global__ void __launch_bounds__(256, 2)
gemm2_kernel(const ushort* __restrict__ A, const ushort* __restrict__ B,
             const float* __restrict__ bias, float* __restrict__ out,
             const int* __restrict__ row_tok, const float* __restrict__ row_w,
             const int* __restrict__ ctrl)
{
    __shared__ ushort As[BM * BK];
    __shared__ ushort Bs[BN * BK];

    const int tid = threadIdx.x;
    const int lane = tid & 63, wid = tid >> 6;
    const int wr = wid >> 1, wc = wid & 1;

    int e = 0, prow0;
    if (ROUTED) {
        if ((int)blockIdx.x >= ctrl[0]) return;
        e     = ctrl[32 + 2 * blockIdx.x];
        prow0 = ctrl[32 + 2 * blockIdx.x + 1];
    } else {
        prow0 = blockIdx.x * BM;
    }
    const int col0 = blockIdx.y * BN;
    const ushort* Be = B + (size_t)e * (DIM * HID);

    const ushort *ag[2], *bg[2];
    int ldso[2];
#pragma unroll
    for (int p = 0; p < 2; p++) {
        int chunk = wid * 2 + p;
        int rit = chunk * 16 + (lane >> 2);
        int kc = (lane & 3) * 8;
        ag[p] = A + (size_t)(prow0 + rit) * HID + kc;
        bg[p] = Be + (size_t)(col0 + rit) * HID + kc;
        ldso[p] = chunk * 512;
    }

    f32x4 zero4 = {0.f, 0.f, 0.f, 0.f};
    f32x4 acc[4][4];
#pragma unroll
    for (int i = 0; i < 4; i++)
#pragma unroll
        for (int j = 0; j < 4; j++) acc[i][j] = zero4;

    const int lrow = lane & 15;
    const int koff = (lane >> 4) * 8;

    for (int kt = 0; kt < HID; kt += BK) {
#pragma unroll
        for (int p = 0; p < 2; p++) {
            gll16(ag[p] + kt, As + ldso[p]);
            gll16(bg[p] + kt, Bs + ldso[p]);
        }
        __syncthreads();
        bf16x8 af[4], bf[4];
#pragma unroll
        for (int i = 0; i < 4; i++)
            af[i] = *(const bf16x8*)(As + (wr * 64 + i * 16 + lrow) * BK + koff);
#pragma unroll
        for (int j = 0; j < 4; j++)
            bf[j] = *(const bf16x8*)(Bs + (wc * 64 + j * 16 + lrow) * BK + koff);
#pragma unroll
        for (int i = 0; i < 4; i++)
#pragma unroll
            for (int j = 0; j < 4; j++)
                acc[i][j] = __builtin_amdgcn_mfma_f32_16x16x32_bf16(af[i], bf[j], acc[i][j], 0, 0, 0);
        __syncthreads();
    }

#pragma unroll
    for (int i = 0; i < 4; i++)
#pragma unroll
        for (int j = 0; j < 4; j++)
#pragma unroll
            for (int r = 0; r < 4; r++) {
                int prow = prow0 + wr * 64 + i * 16 + (lane >> 4) * 4 + r;
                int col = col0 + wc * 64 + j * 16 + (lane & 15);
                float v = acc[i][j][r];
                if (ROUTED) {
                    int tok = row_tok[prow];
                    float w = row_w[prow];
                    atomicAdd(out + (size_t)tok * DIM + col, w * v);
                } else {
                    out[(size_t)prow * DIM + col] = v + bias[col];
                }
            }
}

extern "C" void kernel_launch(void* const* d_in, const int* in_sizes, int n_in,
                              void* d_out, int out_size, void* d_ws, size_t ws_size,
                              hipStream_t stream)
{
    const float* x    = (const float*)d_in[0];
    const float* gw   = (const float*)d_in[1];
    const float* gb   = (const float*)d_in[2];
    const float* bia  = (const float*)d_in[3];
    const float* w1   = (const float*)d_in[4];
    const float* wg   = (const float*)d_in[5];
    const float* w2   = (const float*)d_in[6];
    const float* sw1  = (const float*)d_in[7];
    const float* sb1  = (const float*)d_in[8];
    const float* sw2  = (const float*)d_in[9];
    const float* sb2  = (const float*)d_in[10];
    float* out = (float*)d_out;

    char* ws = (char*)d_ws;
    int*    ctrl   = (int*)   (ws + 0);         // [0]=nm, +8 counts, +16 cursors, +32 tiles
    int*    topk_e = (int*)   (ws + 4096);
    float*  topk_w = (float*) (ws + 102400);
    int*    row_tok= (int*)   (ws + 200704);
    float*  row_w  = (float*) (ws + 302592);
    ushort* xb     = (ushort*)(ws + 404480);
    ushort* w1T    = (ushort*)(ws + 17181696);
    ushort* wgT    = (ushort*)(ws + 31861760);
    ushort* w2T    = (ushort*)(ws + 46541824);
    ushort* sw1T   = (ushort*)(ws + 61221888);
    ushort* sw2T   = (ushort*)(ws + 63319040);
    ushort* hsh    = (ushort*)(ws + 65416192);
    ushort* h1     = (ushort*)(ws + 82193408);  // end ~134.4 MB

    hipMemsetAsync(ctrl, 0, 4096, stream);
    convert_x<<<N_TOK * DIM / 4 / 256, 256, 0, stream>>>(x, xb);
    transpose_convert<<<dim3(32, 32, 23), 256, 0, stream>>>(w1, wg, w2, sw1, sw2,
                                                            w1T, wgT, w2T, sw1T, sw2T);
    gate_kernel<<<N_TOK / 4, 256, 0, stream>>>(x, gw, gb, bia, topk_e, topk_w, ctrl + 8);
    setup_kernel<<<1, 64, 0, stream>>>(ctrl, row_tok, row_w);
    scatter_kernel<<<N_TOK / 256, 256, 0, stream>>>(topk_e, topk_w, ctrl, row_tok, row_w);

    // shared expert: out = silu(x@sw1 + sb1) @ sw2 + sb2   (plain stores init out)
    gemm1_kernel<0, 0, 1><<<dim3(N_TOK / BM, HID / BN), 256, 0, stream>>>(
        xb, sw1T, sw1T, sb1, hsh, row_tok, ctrl);
    gemm2_kernel<0><<<dim3(N_TOK / BM, DIM / BN), 256, 0, stream>>>(
        hsh, sw2T, sb2, out, row_tok, row_w, ctrl);

    // routed experts: h1 = silu(x@w1)*(x@wg); out += w * (h1 @ w2)
    gemm1_kernel<1, 1, 0><<<dim3(MT_ROUTED, HID / BN), 256, 0, stream>>>(
        xb, w1T, wgT, nullptr, h1, row_tok, ctrl);
    gemm2_kernel<1><<<dim3(MT_ROUTED, DIM / BN), 256, 0, stream>>>(
        h1, w2T, nullptr, out, row_tok, row_w, ctrl);
}

// Round 2
// 614.941 us; speedup vs baseline: 1.5905x; 1.5905x over previous
//
#include <hip/hip_runtime.h>
#include <hip/hip_bf16.h>

// DeepSeekMoE: B=4,S=2048,D=1024,H=1024,E=7,NS=1,topk=3. N=8192 tokens.
#define N_TOK 8192
#define DIM   1024
#define HID   1024
#define NE    7
#define BM    128
#define BN    128
#define BK    32
#define MT_ROUTED 199            // max Σ ceil(Ne/128) = 198, +1 slack

typedef __attribute__((ext_vector_type(8))) short bf16x8;
typedef __attribute__((ext_vector_type(4))) float f32x4;

typedef __attribute__((address_space(3))) ushort lds_us_t;
typedef __attribute__((address_space(1))) const ushort glb_us_t;

__device__ __forceinline__ void gll16(const ushort* g, ushort* l) {
    // async global->LDS, 16B per lane; LDS dest is wave-uniform base + lane*16
    __builtin_amdgcn_global_load_lds((glb_us_t*)g, (lds_us_t*)l, 16, 0, 0);
}

__device__ __forceinline__ unsigned short f2bf(float f) {
    unsigned int u = __builtin_bit_cast(unsigned int, f);
    u += 0x7fffu + ((u >> 16) & 1u);   // RNE
    return (unsigned short)(u >> 16);
}

__device__ __forceinline__ float siluf(float v) { return v / (1.f + __expf(-v)); }

// ---------------- gate: logits -> softmax -> top3 -> renorm weights ----------
// Also fuses x fp32->bf16 conversion (we read all of x anyway).
// Block: 256 thr = 4 waves; wave handles 4 tokens; grid 512 blocks.
__global__ void __launch_bounds__(256)
gate_kernel(const float* __restrict__ x, const float* __restrict__ gw,
            const float* __restrict__ gb, const float* __restrict__ bia,
            int* __restrict__ topk_e, float* __restrict__ topk_w,
            int* __restrict__ counts, ushort* __restrict__ xb)
{
    __shared__ float gwT[NE][DIM];   // 28 KB
    __shared__ int cnt[NE];
    const int tid = threadIdx.x;
    if (tid < NE) cnt[tid] = 0;
    // stage gate_w transposed: gw is [D][E] row-major
    for (int t = tid; t < NE * DIM; t += 256) {
        int d = t / NE, e = t - d * NE;
        gwT[e][d] = gw[t];
    }
    __syncthreads();

    const int lane = tid & 63, wid = tid >> 6;
#pragma unroll
    for (int tt = 0; tt < 4; tt++) {
        const int n = blockIdx.x * 16 + wid * 4 + tt;
        const float4* xr = (const float4*)(x + (size_t)n * DIM);
        ushort4* xo = (ushort4*)(xb + (size_t)n * DIM);
        float p[NE];
#pragma unroll
        for (int e = 0; e < NE; e++) p[e] = 0.f;
#pragma unroll
        for (int it = 0; it < 4; it++) {
            int i4 = it * 64 + lane;           // float4 index within row
            float4 v = xr[i4];
            ushort4 o;
            o.x = f2bf(v.x); o.y = f2bf(v.y); o.z = f2bf(v.z); o.w = f2bf(v.w);
            xo[i4] = o;
            int d = i4 * 4;
#pragma unroll
            for (int e = 0; e < NE; e++) {
                float4 g = *(const float4*)&gwT[e][d];
                p[e] += v.x * g.x + v.y * g.y + v.z * g.z + v.w * g.w;
            }
        }
#pragma unroll
        for (int e = 0; e < NE; e++)
            for (int off = 32; off; off >>= 1) p[e] += __shfl_xor(p[e], off);
        if (lane == 0) {
            float l[NE], m = -1e30f;
#pragma unroll
            for (int e = 0; e < NE; e++) { l[e] = p[e] + gb[e]; m = fmaxf(m, l[e]); }
            float s = 0.f;
#pragma unroll
            for (int e = 0; e < NE; e++) { l[e] = __expf(l[e] - m); s += l[e]; }
            float inv = 1.f / s;
#pragma unroll
            for (int e = 0; e < NE; e++) l[e] *= inv;          // probs
            float adj[NE]; bool used[NE];
#pragma unroll
            for (int e = 0; e < NE; e++) { adj[e] = l[e] + bia[e]; used[e] = false; }
            int sel[3]; float w[3]; float ws = 0.f;
            for (int k = 0; k < 3; k++) {
                int b = -1; float bv = -1e30f;
                for (int e = 0; e < NE; e++)
                    if (!used[e] && adj[e] > bv) { bv = adj[e]; b = e; }
                used[b] = true; sel[k] = b; w[k] = l[b]; ws += w[k];
            }
            float iws = 1.f / ws;
            for (int k = 0; k < 3; k++) {
                topk_e[n * 3 + k] = sel[k];
                topk_w[n * 3 + k] = w[k] * iws;
                atomicAdd(&cnt[sel[k]], 1);
            }
        }
    }
    __syncthreads();
    if (tid < NE) atomicAdd(&counts[tid], cnt[tid]);
}

// --------- setup (1 thread): scan counts, tile list, cursors, pad slots ------
__global__ void setup_kernel(int* __restrict__ ctrl, int* __restrict__ row_tok,
                             float* __restrict__ row_w)
{
    if (threadIdx.x != 0 || blockIdx.x != 0) return;
    int* counts = ctrl + 8; int* cursors = ctrl + 16; int* tiles = ctrl + 32;
    int nm = 0, off = 0;
    for (int e = 0; e < NE; e++) {
        int c = counts[e];
        int padc = (c + 127) & ~127;
        cursors[e] = off;
        for (int t = 0; t < padc; t += 128) { tiles[nm * 2] = e; tiles[nm * 2 + 1] = off + t; nm++; }
        for (int i = c; i < padc; i++) { row_tok[off + i] = 0; row_w[off + i] = 0.f; }
        off += padc;
    }
    ctrl[0] = nm;
}

// --------- scatter: token -> per-expert padded row slots ---------------------
__global__ void scatter_kernel(const int* __restrict__ topk_e, const float* __restrict__ topk_w,
                               int* __restrict__ ctrl, int* __restrict__ row_tok,
                               float* __restrict__ row_w)
{
    int n = blockIdx.x * blockDim.x + threadIdx.x;
    if (n >= N_TOK) return;
    int* cursors = ctrl + 16;
    for (int k = 0; k < 3; k++) {
        int e = topk_e[n * 3 + k];
        int slot = atomicAdd(&cursors[e], 1);
        row_tok[slot] = n;
        row_w[slot] = topk_w[n * 3 + k];
    }
}

// --------- transpose+convert all 1024x1024 weight matrices to B^T bf16 -------
__global__ void transpose_convert(const float* __restrict__ w1, const float* __restrict__ wg,
                                  const float* __restrict__ w2, const float* __restrict__ sw1,
                                  const float* __restrict__ sw2,
                                  ushort* __restrict__ w1T, ushort* __restrict__ wgT,
                                  ushort* __restrict__ w2T, ushort* __restrict__ sw1T,
                                  ushort* __restrict__ sw2T)
{
    int z = blockIdx.z;
    const float* src; ushort* dst;
    if (z < 7)       { src = w1 + (size_t)z * (DIM*HID);        dst = w1T + (size_t)z * (DIM*HID); }
    else if (z < 14) { src = wg + (size_t)(z - 7) * (DIM*HID);  dst = wgT + (size_t)(z - 7) * (DIM*HID); }
    else if (z < 21) { src = w2 + (size_t)(z - 14) * (DIM*HID); dst = w2T + (size_t)(z - 14) * (DIM*HID); }
    else if (z == 21){ src = sw1; dst = sw1T; }
    else             { src = sw2; dst = sw2T; }
    __shared__ float t[32][33];
    int bx = blockIdx.x * 32, by = blockIdx.y * 32;
    int lx = threadIdx.x & 31, ly = threadIdx.x >> 5;   // 8 rows per pass
#pragma unroll
    for (int i = 0; i < 32; i += 8)
        t[ly + i][lx] = src[(size_t)(by + ly + i) * 1024 + bx + lx];
    __syncthreads();
#pragma unroll
    for (int i = 0; i < 32; i += 8) {
        int r = ly + i;
        dst[(size_t)(bx + r) * 1024 + by + lx] = f2bf(t[lx][r]);
    }
}

// --------- GEMM1: h = act(x @ W) ; GATED: silu(x@w1)*(x@wg); else silu(+bias) -
// A [rows][1024] bf16 row-major; B^T [1024][1024] bf16 per expert.
template<int GATHER, int GATED, int BIAS>
__global__ void __launch_bounds__(256, 2)
gemm1_kernel(const ushort* __restrict__ A, const ushort* __restrict__ B1,
             const ushort* __restrict__ B2, const float* __restrict__ bias,
             ushort* __restrict__ Hout, const int* __restrict__ row_tok,
             const int* __restrict__ ctrl)
{
    __shared__ ushort As[BM * BK];
    __shared__ ushort Bs1[BN * BK];
    __shared__ ushort Bs2[BN * BK];

    const int tid = threadIdx.x;
    const int lane = tid & 63, wid = tid >> 6;
    const int wr = wid >> 1, wc = wid & 1;

    int e = 0, prow0;
    if (GATHER) {
        if ((int)blockIdx.x >= ctrl[0]) return;
        e     = ctrl[32 + 2 * blockIdx.x];
        prow0 = ctrl[32 + 2 * blockIdx.x + 1];
    } else {
        prow0 = blockIdx.x * BM;
    }
    const int col0 = blockIdx.y * BN;

    const ushort* B1e = B1 + (size_t)e * (DIM * HID);
    const ushort* B2e = B2 + (size_t)e * (DIM * HID);

    const ushort *ag[2], *b1g[2], *b2g[2];
    int ldso[2];
#pragma unroll
    for (int p = 0; p < 2; p++) {
        int chunk = wid * 2 + p;
        int rit = chunk * 16 + (lane >> 2);
        int kc = (lane & 3) * 8;
        int ar = GATHER ? row_tok[prow0 + rit] : (prow0 + rit);
        ag[p]  = A + (size_t)ar * DIM + kc;
        b1g[p] = B1e + (size_t)(col0 + rit) * DIM + kc;
        b2g[p] = B2e + (size_t)(col0 + rit) * DIM + kc;
        ldso[p] = chunk * 512;   // ushort units: 1KB chunks
    }

    f32x4 zero4 = {0.f, 0.f, 0.f, 0.f};
    f32x4 acc1[4][4], acc2[4][4];
#pragma unroll
    for (int i = 0; i < 4; i++)
#pragma unroll
        for (int j = 0; j < 4; j++) { acc1[i][j] = zero4; acc2[i][j] = zero4; }

    const int lrow = lane & 15;
    const int koff = (lane >> 4) * 8;

    for (int kt = 0; kt < DIM; kt += BK) {
#pragma unroll
        for (int p = 0; p < 2; p++) {
            gll16(ag[p] + kt, As + ldso[p]);
            gll16(b1g[p] + kt, Bs1 + ldso[p]);
            if (GATED) gll16(b2g[p] + kt, Bs2 + ldso[p]);
        }
        __syncthreads();
        bf16x8 af[4], bf1[4], bf2[4];
#pragma unroll
        for (int i = 0; i < 4; i++)
            af[i] = *(const bf16x8*)(As + (wr * 64 + i * 16 + lrow) * BK + koff);
#pragma unroll
        for (int j = 0; j < 4; j++) {
            bf1[j] = *(const bf16x8*)(Bs1 + (wc * 64 + j * 16 + lrow) * BK + koff);
            if (GATED) bf2[j] = *(const bf16x8*)(Bs2 + (wc * 64 + j * 16 + lrow) * BK + koff);
        }
#pragma unroll
        for (int i = 0; i < 4; i++)
#pragma unroll
            for (int j = 0; j < 4; j++) {
                acc1[i][j] = __builtin_amdgcn_mfma_f32_16x16x32_bf16(af[i], bf1[j], acc1[i][j], 0, 0, 0);
                if (GATED)
                    acc2[i][j] = __builtin_amdgcn_mfma_f32_16x16x32_bf16(af[i], bf2[j], acc2[i][j], 0, 0, 0);
            }
        __syncthreads();
    }

#pragma unroll
    for (int i = 0; i < 4; i++)
#pragma unroll
        for (int j = 0; j < 4; j++)
#pragma unroll
            for (int r = 0; r < 4; r++) {
                int row = prow0 + wr * 64 + i * 16 + (lane >> 4) * 4 + r;
                int col = col0 + wc * 64 + j * 16 + (lane & 15);
                float v = acc1[i][j][r];
                float h;
                if (GATED) h = siluf(v) * acc2[i][j][r];
                else { if (BIAS) v += bias[col]; h = siluf(v); }
                Hout[(size_t)row * HID + col] = f2bf(h);
            }
}

// --------- GEMM2: y = h @ W2 ; ROUTED: atomicAdd(w*y) ; else store y+bias -----
template<int ROUTED>
__global__ void __launch_bounds__(256, 2)
gemm2_kernel(const ushort* __restrict__ A, const ushort* __restrict__ B,
             const float* __restrict__ bias, float* __restrict__ out,
             const int* __restrict__ row_tok, const float* __restrict__ row_w,
             const int* __restrict__ ctrl)
{
    __shared__ ushort As[BM * BK];
    __shared__ ushort Bs[BN * BK];

    const int tid = threadIdx.x;
    const int lane = tid & 63, wid = tid >> 6;
    const int wr = wid >> 1, wc = wid & 1;

    int e = 0, prow0;
    if (ROUTED) {
        if ((int)blockIdx.x >= ctrl[0]) return;
        e     = ctrl[32 + 2 * blockIdx.x];
        prow0 = ctrl[32 + 2 * blockIdx.x + 1];
    } else {
        prow0 = blockIdx.x * BM;
    }
    const int col0 = blockIdx.y * BN;
    const ushort* Be = B + (size_t)e * (DIM * HID);

    const ushort *ag[2], *bg[2];
    int ldso[2];
#pragma unroll
    for (int p = 0; p < 2; p++) {
        int chunk = wid * 2 + p;
        int rit = chunk * 16 + (lane >> 2);
        int kc = (lane & 3) * 8;
        ag[p] = A + (size_t)(prow0 + rit) * HID + kc;
        bg[p] = Be + (size_t)(col0 + rit) * HID + kc;
        ldso[p] = chunk * 512;
    }

    f32x4 zero4 = {0.f, 0.f, 0.f, 0.f};
    f32x4 acc[4][4];
#pragma unroll
    for (int i = 0; i < 4; i++)
#pragma unroll
        for (int j = 0; j < 4; j++) acc[i][j] = zero4;

    const int lrow = lane & 15;
    const int koff = (lane >> 4) * 8;

    for (int kt = 0; kt < HID; kt += BK) {
#pragma unroll
        for (int p = 0; p < 2; p++) {
            gll16(ag[p] + kt, As + ldso[p]);
            gll16(bg[p] + kt, Bs + ldso[p]);
        }
        __syncthreads();
        bf16x8 af[4], bf[4];
#pragma unroll
        for (int i = 0; i < 4; i++)
            af[i] = *(const bf16x8*)(As + (wr * 64 + i * 16 + lrow) * BK + koff);
#pragma unroll
        for (int j = 0; j < 4; j++)
            bf[j] = *(const bf16x8*)(Bs + (wc * 64 + j * 16 + lrow) * BK + koff);
#pragma unroll
        for (int i = 0; i < 4; i++)
#pragma unroll
            for (int j = 0; j < 4; j++)
                acc[i][j] = __builtin_amdgcn_mfma_f32_16x16x32_bf16(af[i], bf[j], acc[i][j], 0, 0, 0);
        __syncthreads();
    }

#pragma unroll
    for (int i = 0; i < 4; i++)
#pragma unroll
        for (int j = 0; j < 4; j++)
#pragma unroll
            for (int r = 0; r < 4; r++) {
                int prow = prow0 + wr * 64 + i * 16 + (lane >> 4) * 4 + r;
                int col = col0 + wc * 64 + j * 16 + (lane & 15);
                float v = acc[i][j][r];
                if (ROUTED) {
                    int tok = row_tok[prow];
                    float w = row_w[prow];
                    atomicAdd(out + (size_t)tok * DIM + col, w * v);
                } else {
                    out[(size_t)prow * DIM + col] = v + bias[col];
                }
            }
}

extern "C" void kernel_launch(void* const* d_in, const int* in_sizes, int n_in,
                              void* d_out, int out_size, void* d_ws, size_t ws_size,
                              hipStream_t stream)
{
    const float* x    = (const float*)d_in[0];
    const float* gw   = (const float*)d_in[1];
    const float* gb   = (const float*)d_in[2];
    const float* bia  = (const float*)d_in[3];
    const float* w1   = (const float*)d_in[4];
    const float* wg   = (const float*)d_in[5];
    const float* w2   = (const float*)d_in[6];
    const float* sw1  = (const float*)d_in[7];
    const float* sb1  = (const float*)d_in[8];
    const float* sw2  = (const float*)d_in[9];
    const float* sb2  = (const float*)d_in[10];
    float* out = (float*)d_out;

    char* ws = (char*)d_ws;
    int*    ctrl   = (int*)   (ws + 0);         // [0]=nm, +8 counts, +16 cursors, +32 tiles
    int*    topk_e = (int*)   (ws + 4096);
    float*  topk_w = (float*) (ws + 102400);
    int*    row_tok= (int*)   (ws + 200704);
    float*  row_w  = (float*) (ws + 302592);
    ushort* xb     = (ushort*)(ws + 404480);
    ushort* w1T    = (ushort*)(ws + 17181696);
    ushort* wgT    = (ushort*)(ws + 31861760);
    ushort* w2T    = (ushort*)(ws + 46541824);
    ushort* sw1T   = (ushort*)(ws + 61221888);
    ushort* sw2T   = (ushort*)(ws + 63319040);
    ushort* hsh    = (ushort*)(ws + 65416192);
    ushort* h1     = (ushort*)(ws + 82193408);  // end ~134.4 MB

    hipMemsetAsync(ctrl, 0, 4096, stream);
    transpose_convert<<<dim3(32, 32, 23), 256, 0, stream>>>(w1, wg, w2, sw1, sw2,
                                                            w1T, wgT, w2T, sw1T, sw2T);
    gate_kernel<<<N_TOK / 16, 256, 0, stream>>>(x, gw, gb, bia, topk_e, topk_w,
                                                ctrl + 8, xb);
    setup_kernel<<<1, 64, 0, stream>>>(ctrl, row_tok, row_w);
    scatter_kernel<<<N_TOK / 256, 256, 0, stream>>>(topk_e, topk_w, ctrl, row_tok, row_w);

    // shared expert: out = silu(x@sw1 + sb1) @ sw2 + sb2   (plain stores init out)
    gemm1_kernel<0, 0, 1><<<dim3(N_TOK / BM, HID / BN), 256, 0, stream>>>(
        xb, sw1T, sw1T, sb1, hsh, row_tok, ctrl);
    gemm2_kernel<0><<<dim3(N_TOK / BM, DIM / BN), 256, 0, stream>>>(
        hsh, sw2T, sb2, out, row_tok, row_w, ctrl);

    // routed experts: h1 = silu(x@w1)*(x@wg); out += w * (h1 @ w2)
    gemm1_kernel<1, 1, 0><<<dim3(MT_ROUTED, HID / BN), 256, 0, stream>>>(
        xb, w1T, wgT, nullptr, h1, row_tok, ctrl);
    gemm2_kernel<1><<<dim3(MT_ROUTED, DIM / BN), 256, 0, stream>>>(
        h1, w2T, nullptr, out, row_tok, row_w, ctrl);
}

// Round 3
// 499.588 us; speedup vs baseline: 1.9578x; 1.2309x over previous
//
#include <hip/hip_runtime.h>
#include <hip/hip_bf16.h>

// DeepSeekMoE: B=4,S=2048,D=1024,H=1024,E=7,NS=1,topk=3. N=8192 tokens.
#define N_TOK 8192
#define DIM   1024
#define HID   1024
#define NE    7
#define BM    128
#define BN    128
#define BK    32
#define MT_ROUTED 199            // max Σ ceil(Ne/128) = 198, +1 slack

typedef __attribute__((ext_vector_type(8))) short bf16x8;
typedef __attribute__((ext_vector_type(4))) float f32x4;

typedef __attribute__((address_space(3))) ushort lds_us_t;
typedef __attribute__((address_space(1))) const ushort glb_us_t;

__device__ __forceinline__ void gll16(const ushort* g, ushort* l) {
    // async global->LDS, 16B per lane; LDS dest is wave-uniform base + lane*16
    __builtin_amdgcn_global_load_lds((glb_us_t*)g, (lds_us_t*)l, 16, 0, 0);
}

__device__ __forceinline__ unsigned short f2bf(float f) {
    unsigned int u = __builtin_bit_cast(unsigned int, f);
    u += 0x7fffu + ((u >> 16) & 1u);   // RNE
    return (unsigned short)(u >> 16);
}

__device__ __forceinline__ float bf2f(unsigned short b) {
    unsigned int u = ((unsigned int)b) << 16;
    return __builtin_bit_cast(float, u);
}

__device__ __forceinline__ float siluf(float v) { return v / (1.f + __expf(-v)); }

// ---------------- gate: logits -> softmax -> top3 -> renorm weights ----------
// Also fuses x fp32->bf16 conversion (we read all of x anyway).
__global__ void __launch_bounds__(256)
gate_kernel(const float* __restrict__ x, const float* __restrict__ gw,
            const float* __restrict__ gb, const float* __restrict__ bia,
            int* __restrict__ topk_e, float* __restrict__ topk_w,
            int* __restrict__ counts, ushort* __restrict__ xb)
{
    __shared__ float gwT[NE][DIM];   // 28 KB
    __shared__ int cnt[NE];
    const int tid = threadIdx.x;
    if (tid < NE) cnt[tid] = 0;
    for (int t = tid; t < NE * DIM; t += 256) {
        int d = t / NE, e = t - d * NE;
        gwT[e][d] = gw[t];
    }
    __syncthreads();

    const int lane = tid & 63, wid = tid >> 6;
#pragma unroll
    for (int tt = 0; tt < 4; tt++) {
        const int n = blockIdx.x * 16 + wid * 4 + tt;
        const float4* xr = (const float4*)(x + (size_t)n * DIM);
        ushort4* xo = (ushort4*)(xb + (size_t)n * DIM);
        float p[NE];
#pragma unroll
        for (int e = 0; e < NE; e++) p[e] = 0.f;
#pragma unroll
        for (int it = 0; it < 4; it++) {
            int i4 = it * 64 + lane;
            float4 v = xr[i4];
            ushort4 o;
            o.x = f2bf(v.x); o.y = f2bf(v.y); o.z = f2bf(v.z); o.w = f2bf(v.w);
            xo[i4] = o;
            int d = i4 * 4;
#pragma unroll
            for (int e = 0; e < NE; e++) {
                float4 g = *(const float4*)&gwT[e][d];
                p[e] += v.x * g.x + v.y * g.y + v.z * g.z + v.w * g.w;
            }
        }
#pragma unroll
        for (int e = 0; e < NE; e++)
            for (int off = 32; off; off >>= 1) p[e] += __shfl_xor(p[e], off);
        if (lane == 0) {
            float l[NE], m = -1e30f;
#pragma unroll
            for (int e = 0; e < NE; e++) { l[e] = p[e] + gb[e]; m = fmaxf(m, l[e]); }
            float s = 0.f;
#pragma unroll
            for (int e = 0; e < NE; e++) { l[e] = __expf(l[e] - m); s += l[e]; }
            float inv = 1.f / s;
#pragma unroll
            for (int e = 0; e < NE; e++) l[e] *= inv;          // probs
            float adj[NE]; bool used[NE];
#pragma unroll
            for (int e = 0; e < NE; e++) { adj[e] = l[e] + bia[e]; used[e] = false; }
            int sel[3]; float w[3]; float ws = 0.f;
            for (int k = 0; k < 3; k++) {
                int b = -1; float bv = -1e30f;
                for (int e = 0; e < NE; e++)
                    if (!used[e] && adj[e] > bv) { bv = adj[e]; b = e; }
                used[b] = true; sel[k] = b; w[k] = l[b]; ws += w[k];
            }
            float iws = 1.f / ws;
            for (int k = 0; k < 3; k++) {
                topk_e[n * 3 + k] = sel[k];
                topk_w[n * 3 + k] = w[k] * iws;
                atomicAdd(&cnt[sel[k]], 1);
            }
        }
    }
    __syncthreads();
    if (tid < NE) atomicAdd(&counts[tid], cnt[tid]);
}

// --------- setup (1 thread): scan counts, tile list, cursors, pad slots ------
__global__ void setup_kernel(int* __restrict__ ctrl, int* __restrict__ row_tok,
                             float* __restrict__ row_w)
{
    if (threadIdx.x != 0 || blockIdx.x != 0) return;
    int* counts = ctrl + 8; int* cursors = ctrl + 16; int* tiles = ctrl + 32;
    int nm = 0, off = 0;
    for (int e = 0; e < NE; e++) {
        int c = counts[e];
        int padc = (c + 127) & ~127;
        cursors[e] = off;
        for (int t = 0; t < padc; t += 128) { tiles[nm * 2] = e; tiles[nm * 2 + 1] = off + t; nm++; }
        for (int i = c; i < padc; i++) { row_tok[off + i] = 0; row_w[off + i] = 0.f; }
        off += padc;
    }
    ctrl[0] = nm;
}

// --------- scatter: token -> per-expert padded row slots (+ inverse map) -----
__global__ void scatter_kernel(const int* __restrict__ topk_e, const float* __restrict__ topk_w,
                               int* __restrict__ ctrl, int* __restrict__ row_tok,
                               float* __restrict__ row_w, int* __restrict__ slots)
{
    int n = blockIdx.x * blockDim.x + threadIdx.x;
    if (n >= N_TOK) return;
    int* cursors = ctrl + 16;
    for (int k = 0; k < 3; k++) {
        int e = topk_e[n * 3 + k];
        int slot = atomicAdd(&cursors[e], 1);
        row_tok[slot] = n;
        row_w[slot] = topk_w[n * 3 + k];
        slots[n * 3 + k] = slot;
    }
}

// --------- transpose+convert all 1024x1024 weight matrices to B^T bf16 -------
__global__ void transpose_convert(const float* __restrict__ w1, const float* __restrict__ wg,
                                  const float* __restrict__ w2, const float* __restrict__ sw1,
                                  const float* __restrict__ sw2,
                                  ushort* __restrict__ w1T, ushort* __restrict__ wgT,
                                  ushort* __restrict__ w2T, ushort* __restrict__ sw1T,
                                  ushort* __restrict__ sw2T)
{
    int z = blockIdx.z;
    const float* src; ushort* dst;
    if (z < 7)       { src = w1 + (size_t)z * (DIM*HID);        dst = w1T + (size_t)z * (DIM*HID); }
    else if (z < 14) { src = wg + (size_t)(z - 7) * (DIM*HID);  dst = wgT + (size_t)(z - 7) * (DIM*HID); }
    else if (z < 21) { src = w2 + (size_t)(z - 14) * (DIM*HID); dst = w2T + (size_t)(z - 14) * (DIM*HID); }
    else if (z == 21){ src = sw1; dst = sw1T; }
    else             { src = sw2; dst = sw2T; }
    __shared__ float t[32][33];
    int bx = blockIdx.x * 32, by = blockIdx.y * 32;
    int lx = threadIdx.x & 31, ly = threadIdx.x >> 5;
#pragma unroll
    for (int i = 0; i < 32; i += 8)
        t[ly + i][lx] = src[(size_t)(by + ly + i) * 1024 + bx + lx];
    __syncthreads();
#pragma unroll
    for (int i = 0; i < 32; i += 8) {
        int r = ly + i;
        dst[(size_t)(bx + r) * 1024 + by + lx] = f2bf(t[lx][r]);
    }
}

// --------- GEMM1: h = act(x @ W) ; GATED: silu(x@w1)*(x@wg); else silu(+bias) -
template<int GATHER, int GATED, int BIAS>
__global__ void __launch_bounds__(256, 2)
gemm1_kernel(const ushort* __restrict__ A, const ushort* __restrict__ B1,
             const ushort* __restrict__ B2, const float* __restrict__ bias,
             ushort* __restrict__ Hout, const int* __restrict__ row_tok,
             const int* __restrict__ ctrl)
{
    __shared__ ushort As[BM * BK];
    __shared__ ushort Bs1[BN * BK];
    __shared__ ushort Bs2[BN * BK];

    const int tid = threadIdx.x;
    const int lane = tid & 63, wid = tid >> 6;
    const int wr = wid >> 1, wc = wid & 1;

    int e = 0, prow0;
    if (GATHER) {
        if ((int)blockIdx.x >= ctrl[0]) return;
        e     = ctrl[32 + 2 * blockIdx.x];
        prow0 = ctrl[32 + 2 * blockIdx.x + 1];
    } else {
        prow0 = blockIdx.x * BM;
    }
    const int col0 = blockIdx.y * BN;

    const ushort* B1e = B1 + (size_t)e * (DIM * HID);
    const ushort* B2e = B2 + (size_t)e * (DIM * HID);

    const ushort *ag[2], *b1g[2], *b2g[2];
    int ldso[2];
#pragma unroll
    for (int p = 0; p < 2; p++) {
        int chunk = wid * 2 + p;
        int rit = chunk * 16 + (lane >> 2);
        int kc = (lane & 3) * 8;
        int ar = GATHER ? row_tok[prow0 + rit] : (prow0 + rit);
        ag[p]  = A + (size_t)ar * DIM + kc;
        b1g[p] = B1e + (size_t)(col0 + rit) * DIM + kc;
        b2g[p] = B2e + (size_t)(col0 + rit) * DIM + kc;
        ldso[p] = chunk * 512;
    }

    f32x4 zero4 = {0.f, 0.f, 0.f, 0.f};
    f32x4 acc1[4][4], acc2[4][4];
#pragma unroll
    for (int i = 0; i < 4; i++)
#pragma unroll
        for (int j = 0; j < 4; j++) { acc1[i][j] = zero4; acc2[i][j] = zero4; }

    const int lrow = lane & 15;
    const int koff = (lane >> 4) * 8;

    for (int kt = 0; kt < DIM; kt += BK) {
#pragma unroll
        for (int p = 0; p < 2; p++) {
            gll16(ag[p] + kt, As + ldso[p]);
            gll16(b1g[p] + kt, Bs1 + ldso[p]);
            if (GATED) gll16(b2g[p] + kt, Bs2 + ldso[p]);
        }
        __syncthreads();
        bf16x8 af[4], bf1[4], bf2[4];
#pragma unroll
        for (int i = 0; i < 4; i++)
            af[i] = *(const bf16x8*)(As + (wr * 64 + i * 16 + lrow) * BK + koff);
#pragma unroll
        for (int j = 0; j < 4; j++) {
            bf1[j] = *(const bf16x8*)(Bs1 + (wc * 64 + j * 16 + lrow) * BK + koff);
            if (GATED) bf2[j] = *(const bf16x8*)(Bs2 + (wc * 64 + j * 16 + lrow) * BK + koff);
        }
#pragma unroll
        for (int i = 0; i < 4; i++)
#pragma unroll
            for (int j = 0; j < 4; j++) {
                acc1[i][j] = __builtin_amdgcn_mfma_f32_16x16x32_bf16(af[i], bf1[j], acc1[i][j], 0, 0, 0);
                if (GATED)
                    acc2[i][j] = __builtin_amdgcn_mfma_f32_16x16x32_bf16(af[i], bf2[j], acc2[i][j], 0, 0, 0);
            }
        __syncthreads();
    }

#pragma unroll
    for (int i = 0; i < 4; i++)
#pragma unroll
        for (int j = 0; j < 4; j++)
#pragma unroll
            for (int r = 0; r < 4; r++) {
                int row = prow0 + wr * 64 + i * 16 + (lane >> 4) * 4 + r;
                int col = col0 + wc * 64 + j * 16 + (lane & 15);
                float v = acc1[i][j][r];
                float h;
                if (GATED) h = siluf(v) * acc2[i][j][r];
                else { if (BIAS) v += bias[col]; h = siluf(v); }
                Hout[(size_t)row * HID + col] = f2bf(h);
            }
}

// --------- GEMM2: y = h @ W2
// MODE 0: shared  -> out[row] = y + bias (fp32 stores, initializes d_out)
// MODE 1: routed  -> yout[row] = bf16(y) (combine pass applies weights)
// MODE 2: routed fallback -> atomicAdd(out + tok, w*y)  (small-ws path)
template<int MODE>
__global__ void __launch_bounds__(256, 2)
gemm2_kernel(const ushort* __restrict__ A, const ushort* __restrict__ B,
             const float* __restrict__ bias, float* __restrict__ out,
             ushort* __restrict__ yout, const int* __restrict__ row_tok,
             const float* __restrict__ row_w, const int* __restrict__ ctrl)
{
    __shared__ ushort As[BM * BK];
    __shared__ ushort Bs[BN * BK];

    const int tid = threadIdx.x;
    const int lane = tid & 63, wid = tid >> 6;
    const int wr = wid >> 1, wc = wid & 1;

    int e = 0, prow0;
    if (MODE != 0) {
        if ((int)blockIdx.x >= ctrl[0]) return;
        e     = ctrl[32 + 2 * blockIdx.x];
        prow0 = ctrl[32 + 2 * blockIdx.x + 1];
    } else {
        prow0 = blockIdx.x * BM;
    }
    const int col0 = blockIdx.y * BN;
    const ushort* Be = B + (size_t)e * (DIM * HID);

    const ushort *ag[2], *bg[2];
    int ldso[2];
#pragma unroll
    for (int p = 0; p < 2; p++) {
        int chunk = wid * 2 + p;
        int rit = chunk * 16 + (lane >> 2);
        int kc = (lane & 3) * 8;
        ag[p] = A + (size_t)(prow0 + rit) * HID + kc;
        bg[p] = Be + (size_t)(col0 + rit) * HID + kc;
        ldso[p] = chunk * 512;
    }

    f32x4 zero4 = {0.f, 0.f, 0.f, 0.f};
    f32x4 acc[4][4];
#pragma unroll
    for (int i = 0; i < 4; i++)
#pragma unroll
        for (int j = 0; j < 4; j++) acc[i][j] = zero4;

    const int lrow = lane & 15;
    const int koff = (lane >> 4) * 8;

    for (int kt = 0; kt < HID; kt += BK) {
#pragma unroll
        for (int p = 0; p < 2; p++) {
            gll16(ag[p] + kt, As + ldso[p]);
            gll16(bg[p] + kt, Bs + ldso[p]);
        }
        __syncthreads();
        bf16x8 af[4], bf[4];
#pragma unroll
        for (int i = 0; i < 4; i++)
            af[i] = *(const bf16x8*)(As + (wr * 64 + i * 16 + lrow) * BK + koff);
#pragma unroll
        for (int j = 0; j < 4; j++)
            bf[j] = *(const bf16x8*)(Bs + (wc * 64 + j * 16 + lrow) * BK + koff);
#pragma unroll
        for (int i = 0; i < 4; i++)
#pragma unroll
            for (int j = 0; j < 4; j++)
                acc[i][j] = __builtin_amdgcn_mfma_f32_16x16x32_bf16(af[i], bf[j], acc[i][j], 0, 0, 0);
        __syncthreads();
    }

#pragma unroll
    for (int i = 0; i < 4; i++)
#pragma unroll
        for (int j = 0; j < 4; j++)
#pragma unroll
            for (int r = 0; r < 4; r++) {
                int prow = prow0 + wr * 64 + i * 16 + (lane >> 4) * 4 + r;
                int col = col0 + wc * 64 + j * 16 + (lane & 15);
                float v = acc[i][j][r];
                if (MODE == 0) {
                    out[(size_t)prow * DIM + col] = v + bias[col];
                } else if (MODE == 1) {
                    yout[(size_t)prow * DIM + col] = f2bf(v);
                } else {
                    int tok = row_tok[prow];
                    float w = row_w[prow];
                    atomicAdd(out + (size_t)tok * DIM + col, w * v);
                }
            }
}

// --------- combine: out[n] += sum_k w_k * y_rout[slot_k(n)] ------------------
__global__ void __launch_bounds__(256)
combine_kernel(const ushort* __restrict__ y, const int* __restrict__ slots,
               const float* __restrict__ topk_w, float* __restrict__ out)
{
    __shared__ int ss[3];
    __shared__ float sw[3];
    const int n = blockIdx.x, tid = threadIdx.x;
    if (tid < 3) { ss[tid] = slots[n * 3 + tid]; sw[tid] = topk_w[n * 3 + tid]; }
    __syncthreads();
    float4* o4 = (float4*)(out + (size_t)n * DIM);
    float4 o = o4[tid];
#pragma unroll
    for (int k = 0; k < 3; k++) {
        const ushort4 yv = *(const ushort4*)(y + (size_t)ss[k] * DIM + tid * 4);
        float w = sw[k];
        o.x += w * bf2f(yv.x);
        o.y += w * bf2f(yv.y);
        o.z += w * bf2f(yv.z);
        o.w += w * bf2f(yv.w);
    }
    o4[tid] = o;
}

extern "C" void kernel_launch(void* const* d_in, const int* in_sizes, int n_in,
                              void* d_out, int out_size, void* d_ws, size_t ws_size,
                              hipStream_t stream)
{
    const float* x    = (const float*)d_in[0];
    const float* gw   = (const float*)d_in[1];
    const float* gb   = (const float*)d_in[2];
    const float* bia  = (const float*)d_in[3];
    const float* w1   = (const float*)d_in[4];
    const float* wg   = (const float*)d_in[5];
    const float* w2   = (const float*)d_in[6];
    const float* sw1  = (const float*)d_in[7];
    const float* sb1  = (const float*)d_in[8];
    const float* sw2  = (const float*)d_in[9];
    const float* sb2  = (const float*)d_in[10];
    float* out = (float*)d_out;

    char* ws = (char*)d_ws;
    int*    ctrl   = (int*)   (ws + 0);         // [0]=nm, +8 counts, +16 cursors, +32 tiles
    int*    topk_e = (int*)   (ws + 4096);
    float*  topk_w = (float*) (ws + 102400);
    int*    row_tok= (int*)   (ws + 200704);
    float*  row_w  = (float*) (ws + 302592);
    ushort* xb     = (ushort*)(ws + 404480);
    ushort* w1T    = (ushort*)(ws + 17181696);
    ushort* wgT    = (ushort*)(ws + 31861760);
    ushort* w2T    = (ushort*)(ws + 46541824);
    ushort* sw1T   = (ushort*)(ws + 61221888);
    ushort* sw2T   = (ushort*)(ws + 63319040);
    ushort* hsh    = (ushort*)(ws + 65416192);
    ushort* h1     = (ushort*)(ws + 82193408);  // 25472*1024*2 = 52,166,656
    int*    slots  = (int*)   (ws + 134360064); // 8192*3*4 = 98,304
    ushort* y_rout = (ushort*)(ws + 134458368); // 52,166,656 -> end 186,625,024
    const bool twopass = ws_size >= 186625024ull;

    hipMemsetAsync(ctrl, 0, 4096, stream);
    transpose_convert<<<dim3(32, 32, 23), 256, 0, stream>>>(w1, wg, w2, sw1, sw2,
                                                            w1T, wgT, w2T, sw1T, sw2T);
    gate_kernel<<<N_TOK / 16, 256, 0, stream>>>(x, gw, gb, bia, topk_e, topk_w,
                                                ctrl + 8, xb);
    setup_kernel<<<1, 64, 0, stream>>>(ctrl, row_tok, row_w);
    scatter_kernel<<<N_TOK / 256, 256, 0, stream>>>(topk_e, topk_w, ctrl, row_tok,
                                                    row_w, slots);

    // shared expert: out = silu(x@sw1 + sb1) @ sw2 + sb2   (plain stores init out)
    gemm1_kernel<0, 0, 1><<<dim3(N_TOK / BM, HID / BN), 256, 0, stream>>>(
        xb, sw1T, sw1T, sb1, hsh, row_tok, ctrl);
    gemm2_kernel<0><<<dim3(N_TOK / BM, DIM / BN), 256, 0, stream>>>(
        hsh, sw2T, sb2, out, nullptr, row_tok, row_w, ctrl);

    // routed experts: h1 = silu(x@w1)*(x@wg); out += w * (h1 @ w2)
    gemm1_kernel<1, 1, 0><<<dim3(MT_ROUTED, HID / BN), 256, 0, stream>>>(
        xb, w1T, wgT, nullptr, h1, row_tok, ctrl);
    if (twopass) {
        gemm2_kernel<1><<<dim3(MT_ROUTED, DIM / BN), 256, 0, stream>>>(
            h1, w2T, nullptr, out, y_rout, row_tok, row_w, ctrl);
        combine_kernel<<<N_TOK, 256, 0, stream>>>(y_rout, slots, topk_w, out);
    } else {
        gemm2_kernel<2><<<dim3(MT_ROUTED, DIM / BN), 256, 0, stream>>>(
            h1, w2T, nullptr, out, nullptr, row_tok, row_w, ctrl);
    }
}

// Round 5
// 477.189 us; speedup vs baseline: 2.0497x; 1.0469x over previous
//
#include <hip/hip_runtime.h>
#include <hip/hip_bf16.h>

// DeepSeekMoE: B=4,S=2048,D=1024,H=1024,E=7,NS=1,topk=3. N=8192 tokens.
#define N_TOK 8192
#define DIM   1024
#define NE    7
#define MT_TILES 136   // <= 103 routed tiles + 32 shared + slack

typedef __attribute__((ext_vector_type(8))) short bf16x8;
typedef __attribute__((ext_vector_type(4))) float f32x4;

typedef __attribute__((address_space(3))) ushort lds_us_t;
typedef __attribute__((address_space(1))) const ushort glb_us_t;

__device__ __forceinline__ void gll16(const ushort* g, ushort* l) {
    __builtin_amdgcn_global_load_lds((glb_us_t*)g, (lds_us_t*)l, 16, 0, 0);
}

__device__ __forceinline__ unsigned short f2bf(float f) {
    unsigned int u = __builtin_bit_cast(unsigned int, f);
    u += 0x7fffu + ((u >> 16) & 1u);   // RNE
    return (unsigned short)(u >> 16);
}

__device__ __forceinline__ float bf2f(unsigned short b) {
    unsigned int u = ((unsigned int)b) << 16;
    return __builtin_bit_cast(float, u);
}

__device__ __forceinline__ float siluf(float v) { return v / (1.f + __expf(-v)); }

// ---------------- gate: logits -> softmax -> top3 -> renorm weights ----------
// Fuses x fp32->bf16 conversion.
__global__ void __launch_bounds__(256)
gate_kernel(const float* __restrict__ x, const float* __restrict__ gw,
            const float* __restrict__ gb, const float* __restrict__ bia,
            int* __restrict__ topk_e, float* __restrict__ topk_w,
            int* __restrict__ counts, ushort* __restrict__ xb)
{
    __shared__ float gwT[NE][DIM];   // 28 KB
    __shared__ int cnt[NE];
    const int tid = threadIdx.x;
    if (tid < NE) cnt[tid] = 0;
    for (int t = tid; t < NE * DIM; t += 256) {
        int d = t / NE, e = t - d * NE;
        gwT[e][d] = gw[t];
    }
    __syncthreads();

    const int lane = tid & 63, wid = tid >> 6;
#pragma unroll
    for (int tt = 0; tt < 4; tt++) {
        const int n = blockIdx.x * 16 + wid * 4 + tt;
        const float4* xr = (const float4*)(x + (size_t)n * DIM);
        ushort4* xo = (ushort4*)(xb + (size_t)n * DIM);
        float p[NE];
#pragma unroll
        for (int e = 0; e < NE; e++) p[e] = 0.f;
#pragma unroll
        for (int it = 0; it < 4; it++) {
            int i4 = it * 64 + lane;
            float4 v = xr[i4];
            ushort4 o;
            o.x = f2bf(v.x); o.y = f2bf(v.y); o.z = f2bf(v.z); o.w = f2bf(v.w);
            xo[i4] = o;
            int d = i4 * 4;
#pragma unroll
            for (int e = 0; e < NE; e++) {
                float4 g = *(const float4*)&gwT[e][d];
                p[e] += v.x * g.x + v.y * g.y + v.z * g.z + v.w * g.w;
            }
        }
#pragma unroll
        for (int e = 0; e < NE; e++)
            for (int off = 32; off; off >>= 1) p[e] += __shfl_xor(p[e], off);
        if (lane == 0) {
            float l[NE], m = -1e30f;
#pragma unroll
            for (int e = 0; e < NE; e++) { l[e] = p[e] + gb[e]; m = fmaxf(m, l[e]); }
            float s = 0.f;
#pragma unroll
            for (int e = 0; e < NE; e++) { l[e] = __expf(l[e] - m); s += l[e]; }
            float inv = 1.f / s;
#pragma unroll
            for (int e = 0; e < NE; e++) l[e] *= inv;          // probs
            float adj[NE]; bool used[NE];
#pragma unroll
            for (int e = 0; e < NE; e++) { adj[e] = l[e] + bia[e]; used[e] = false; }
            int sel[3]; float w[3]; float ws = 0.f;
            for (int k = 0; k < 3; k++) {
                int b = -1; float bv = -1e30f;
                for (int e = 0; e < NE; e++)
                    if (!used[e] && adj[e] > bv) { bv = adj[e]; b = e; }
                used[b] = true; sel[k] = b; w[k] = l[b]; ws += w[k];
            }
            float iws = 1.f / ws;
            for (int k = 0; k < 3; k++) {
                topk_e[n * 3 + k] = sel[k];
                topk_w[n * 3 + k] = w[k] * iws;
                atomicAdd(&cnt[sel[k]], 1);
            }
        }
    }
    __syncthreads();
    if (tid < NE) atomicAdd(&counts[tid], cnt[tid]);
}

// --------- setup (1 thread): 256-pad scan, tile list (+shared tiles) ---------
__global__ void setup_kernel(int* __restrict__ ctrl, int* __restrict__ row_tok)
{
    if (threadIdx.x != 0 || blockIdx.x != 0) return;
    int* counts = ctrl + 8; int* cursors = ctrl + 16; int* tiles = ctrl + 32;
    int nm = 0, off = 0;
    for (int e = 0; e < NE; e++) {
        int c = counts[e];
        int padc = (c + 255) & ~255;
        cursors[e] = off;
        for (int t = 0; t < padc; t += 256) { tiles[nm*2] = e; tiles[nm*2+1] = off + t; nm++; }
        for (int i = c; i < padc; i++) row_tok[off + i] = 0;
        off += padc;
    }
    ctrl[2] = off;                       // shared_base
    for (int t = 0; t < N_TOK; t += 256) { tiles[nm*2] = NE; tiles[nm*2+1] = off + t; nm++; }
    ctrl[1] = off + N_TOK;               // total rows
    ctrl[0] = nm;                        // tile count
}

// --------- identity fill for shared region -----------------------------------
__global__ void ident_kernel(const int* __restrict__ ctrl, int* __restrict__ row_tok)
{
    int n = blockIdx.x * 256 + threadIdx.x;
    row_tok[ctrl[2] + n] = n;
}

// --------- scatter: token -> per-expert padded slots (+ inverse map) ---------
__global__ void scatter_kernel(const int* __restrict__ topk_e, const float* __restrict__ topk_w,
                               int* __restrict__ ctrl, int* __restrict__ row_tok,
                               int* __restrict__ slots)
{
    int n = blockIdx.x * blockDim.x + threadIdx.x;
    if (n >= N_TOK) return;
    int* cursors = ctrl + 16;
    for (int k = 0; k < 3; k++) {
        int e = topk_e[n * 3 + k];
        int slot = atomicAdd(&cursors[e], 1);
        row_tok[slot] = n;
        slots[n * 3 + k] = slot;
    }
}

// --------- transpose+convert weights to B^T bf16 -----------------------------
// z 0-6: w1->w1T[e]; 7-13: wg->wgT[e]; 14-20: w2->w2T[e]; 21: sw1->w1T[7]; 22: sw2->w2T[7]
__global__ void transpose_convert(const float* __restrict__ w1, const float* __restrict__ wg,
                                  const float* __restrict__ w2, const float* __restrict__ sw1,
                                  const float* __restrict__ sw2,
                                  ushort* __restrict__ w1T, ushort* __restrict__ wgT,
                                  ushort* __restrict__ w2T)
{
    int z = blockIdx.z;
    const float* src; ushort* dst;
    if (z < 7)       { src = w1 + (size_t)z * (DIM*DIM);        dst = w1T + (size_t)z * (DIM*DIM); }
    else if (z < 14) { src = wg + (size_t)(z - 7) * (DIM*DIM);  dst = wgT + (size_t)(z - 7) * (DIM*DIM); }
    else if (z < 21) { src = w2 + (size_t)(z - 14) * (DIM*DIM); dst = w2T + (size_t)(z - 14) * (DIM*DIM); }
    else if (z == 21){ src = sw1; dst = w1T + (size_t)NE * (DIM*DIM); }
    else             { src = sw2; dst = w2T + (size_t)NE * (DIM*DIM); }
    __shared__ float t[32][33];
    int bx = blockIdx.x * 32, by = blockIdx.y * 32;
    int lx = threadIdx.x & 31, ly = threadIdx.x >> 5;
#pragma unroll
    for (int i = 0; i < 32; i += 8)
        t[ly + i][lx] = src[(size_t)(by + ly + i) * DIM + bx + lx];
    __syncthreads();
#pragma unroll
    for (int i = 0; i < 32; i += 8) {
        int r = ly + i;
        dst[(size_t)(bx + r) * DIM + by + lx] = f2bf(t[lx][r]);
    }
}

// ============ deep-pipelined GEMM: BM=256 BN=128 BK=32, quad-buffer ==========
// Dual-row packed LDS: data for (row r, k-chunk c) at ushort
//   (r>>1)*64 + (((((r&1)<<2)|c) ^ ((r>>1)&7))*8,  c = k/8 in 0..3.
// global_load_lds writes linearly; the source address is inverse-swizzled so
// the involution matches on both sides (rule #21). 2 lanes/bank (free).
// Pipeline: stage t+2 while computing t; vmcnt leaves next tile in flight.

// ---- G1: h = silu(x@w1)*(x@wg)  (e<7)  |  silu(x@sw1 + sb1)  (e==7) ---------
__global__ void __launch_bounds__(512, 2)
g1_kernel(const ushort* __restrict__ Xb, const ushort* __restrict__ W1,
          const ushort* __restrict__ WG, const float* __restrict__ sb1,
          ushort* __restrict__ H, const int* __restrict__ row_tok,
          const int* __restrict__ ctrl)
{
    __shared__ ushort lds[65536];   // 128 KB: 4 bufs x (8192 A + 4096 B1 + 4096 B2)
    const int bx = blockIdx.x;
    if (bx >= ctrl[0]) return;
    const int e     = ctrl[32 + 2*bx];
    const int slot0 = ctrl[32 + 2*bx + 1];
    const int col0  = blockIdx.y * 128;
    const bool gated = (e != NE);
    const int tt = threadIdx.x;
    const int lane = tt & 63, wid = tt >> 6;
    const int wm = wid >> 1, wn = wid & 1;
    const int wofs = wid * 512;

    // staging source (inverse-swizzled global address)
    const int slog = (tt & 7) ^ ((tt >> 3) & 7);
    const int kk0 = (slog & 3) * 8;
    const int r0 = ((tt >> 3) << 1) + (slog >> 2);
    const ushort* pA0 = Xb + (size_t)row_tok[slot0 + r0] * DIM + kk0;
    const ushort* pA1 = Xb + (size_t)row_tok[slot0 + r0 + 128] * DIM + kk0;
    const ushort* B1e = W1 + (size_t)e * (DIM*DIM);
    const ushort* B2e = gated ? (WG + (size_t)e * (DIM*DIM))
                              : (W1 + (size_t)NE * (DIM*DIM));
    const ushort* pB1 = B1e + (size_t)(col0 + r0) * DIM + kk0;
    const ushort* pB2 = B2e + (size_t)(col0 + r0) * DIM + kk0;

    // fragment read offsets (swizzled)
    const int hi = lane >> 4, lr = lane & 15;
    int aoff[4], boff[4];
#pragma unroll
    for (int m = 0; m < 4; m++) {
        int row = wm*64 + m*16 + lr;
        int lrow = row >> 1;
        int sl = ((row & 1) << 2) | hi;
        aoff[m] = lrow*64 + (sl ^ (lrow & 7))*8;
    }
#pragma unroll
    for (int n = 0; n < 4; n++) {
        int oc = wn*64 + n*16 + lr;
        int lrow = oc >> 1;
        int sl = ((oc & 1) << 2) | hi;
        boff[n] = lrow*64 + (sl ^ (lrow & 7))*8;
    }

    f32x4 zero4 = {0.f, 0.f, 0.f, 0.f};
    f32x4 acc1[4][4], acc2[4][4];
#pragma unroll
    for (int m = 0; m < 4; m++)
#pragma unroll
        for (int n = 0; n < 4; n++) { acc1[m][n] = zero4; acc2[m][n] = zero4; }

    auto stage = [&](int buf, int kte) {
        ushort* b = &lds[buf * 16384];
        gll16(pA0 + kte, b + wofs);
        gll16(pA1 + kte, b + 4096 + wofs);
        gll16(pB1 + kte, b + 8192 + wofs);
        gll16(pB2 + kte, b + 12288 + wofs);
    };
    auto compute = [&](int buf) {
        const ushort* Ab = &lds[buf * 16384];
        const ushort* Bb = Ab + 8192;
        bf16x8 a[4], bv[4];
#pragma unroll
        for (int m = 0; m < 4; m++) a[m] = *(const bf16x8*)(Ab + aoff[m]);
#pragma unroll
        for (int n = 0; n < 4; n++) bv[n] = *(const bf16x8*)(Bb + boff[n]);
        __builtin_amdgcn_s_setprio(1);
#pragma unroll
        for (int m = 0; m < 4; m++)
#pragma unroll
            for (int n = 0; n < 4; n++)
                acc1[m][n] = __builtin_amdgcn_mfma_f32_16x16x32_bf16(a[m], bv[n], acc1[m][n], 0, 0, 0);
        __builtin_amdgcn_s_setprio(0);
        if (gated) {
            const ushort* B2b = Ab + 12288;
            bf16x8 b2[4];
#pragma unroll
            for (int n = 0; n < 4; n++) b2[n] = *(const bf16x8*)(B2b + boff[n]);
            __builtin_amdgcn_s_setprio(1);
#pragma unroll
            for (int m = 0; m < 4; m++)
#pragma unroll
                for (int n = 0; n < 4; n++)
                    acc2[m][n] = __builtin_amdgcn_mfma_f32_16x16x32_bf16(a[m], b2[n], acc2[m][n], 0, 0, 0);
            __builtin_amdgcn_s_setprio(0);
        }
    };

    stage(0, 0); stage(1, 32);
    asm volatile("s_waitcnt vmcnt(4)" ::: "memory");
    __builtin_amdgcn_s_barrier();
    asm volatile("" ::: "memory");
    for (int t = 0; t < 30; ++t) {
        stage((t + 2) & 3, (t + 2) * 32);
        compute(t & 3);
        asm volatile("s_waitcnt vmcnt(4)" ::: "memory");
        __builtin_amdgcn_s_barrier();
        asm volatile("" ::: "memory");
    }
    compute(2);
    asm volatile("s_waitcnt vmcnt(0)" ::: "memory");
    __builtin_amdgcn_s_barrier();
    asm volatile("" ::: "memory");
    compute(3);

    // epilogue: SwiGLU (routed) / bias-silu (shared)
#pragma unroll
    for (int m = 0; m < 4; m++)
#pragma unroll
        for (int n = 0; n < 4; n++)
#pragma unroll
            for (int r = 0; r < 4; r++) {
                int row = slot0 + wm*64 + m*16 + hi*4 + r;
                int col = col0 + wn*64 + n*16 + lr;
                float v1 = acc1[m][n][r];
                float h = gated ? siluf(v1) * acc2[m][n][r]
                                : siluf(v1 + sb1[col]);
                H[(size_t)row * DIM + col] = f2bf(h);
            }
}

// ---- G2: y = h @ w2 ; routed -> y2 bf16 ; shared -> out = y + sb2 (fp32) ----
__global__ void __launch_bounds__(512, 2)
g2_kernel(const ushort* __restrict__ H, const ushort* __restrict__ W2,
          const float* __restrict__ sb2, float* __restrict__ out,
          ushort* __restrict__ y2, const int* __restrict__ ctrl)
{
    __shared__ ushort lds[49152];   // 96 KB: 4 bufs x (8192 A + 4096 B)
    const int bx = blockIdx.x;
    if (bx >= ctrl[0]) return;
    const int e     = ctrl[32 + 2*bx];
    const int slot0 = ctrl[32 + 2*bx + 1];
    const int sbase = ctrl[2];
    const int col0  = blockIdx.y * 128;
    const int tt = threadIdx.x;
    const int lane = tt & 63, wid = tt >> 6;
    const int wm = wid >> 1, wn = wid & 1;
    const int wofs = wid * 512;

    const int slog = (tt & 7) ^ ((tt >> 3) & 7);
    const int kk0 = (slog & 3) * 8;
    const int r0 = ((tt >> 3) << 1) + (slog >> 2);
    const ushort* pA0 = H + (size_t)(slot0 + r0) * DIM + kk0;
    const ushort* pA1 = H + (size_t)(slot0 + r0 + 128) * DIM + kk0;
    const ushort* Be  = W2 + (size_t)e * (DIM*DIM);
    const ushort* pB1 = Be + (size_t)(col0 + r0) * DIM + kk0;

    const int hi = lane >> 4, lr = lane & 15;
    int aoff[4], boff[4];
#pragma unroll
    for (int m = 0; m < 4; m++) {
        int row = wm*64 + m*16 + lr;
        int lrow = row >> 1;
        int sl = ((row & 1) << 2) | hi;
        aoff[m] = lrow*64 + (sl ^ (lrow & 7))*8;
    }
#pragma unroll
    for (int n = 0; n < 4; n++) {
        int oc = wn*64 + n*16 + lr;
        int lrow = oc >> 1;
        int sl = ((oc & 1) << 2) | hi;
        boff[n] = lrow*64 + (sl ^ (lrow & 7))*8;
    }

    f32x4 zero4 = {0.f, 0.f, 0.f, 0.f};
    f32x4 acc[4][4];
#pragma unroll
    for (int m = 0; m < 4; m++)
#pragma unroll
        for (int n = 0; n < 4; n++) acc[m][n] = zero4;

    auto stage = [&](int buf, int kte) {
        ushort* b = &lds[buf * 12288];
        gll16(pA0 + kte, b + wofs);
        gll16(pA1 + kte, b + 4096 + wofs);
        gll16(pB1 + kte, b + 8192 + wofs);
    };
    auto compute = [&](int buf) {
        const ushort* Ab = &lds[buf * 12288];
        const ushort* Bb = Ab + 8192;
        bf16x8 a[4], bv[4];
#pragma unroll
        for (int m = 0; m < 4; m++) a[m] = *(const bf16x8*)(Ab + aoff[m]);
#pragma unroll
        for (int n = 0; n < 4; n++) bv[n] = *(const bf16x8*)(Bb + boff[n]);
        __builtin_amdgcn_s_setprio(1);
#pragma unroll
        for (int m = 0; m < 4; m++)
#pragma unroll
            for (int n = 0; n < 4; n++)
                acc[m][n] = __builtin_amdgcn_mfma_f32_16x16x32_bf16(a[m], bv[n], acc[m][n], 0, 0, 0);
        __builtin_amdgcn_s_setprio(0);
    };

    stage(0, 0); stage(1, 32);
    asm volatile("s_waitcnt vmcnt(3)" ::: "memory");
    __builtin_amdgcn_s_barrier();
    asm volatile("" ::: "memory");
    for (int t = 0; t < 30; ++t) {
        stage((t + 2) & 3, (t + 2) * 32);
        compute(t & 3);
        asm volatile("s_waitcnt vmcnt(3)" ::: "memory");
        __builtin_amdgcn_s_barrier();
        asm volatile("" ::: "memory");
    }
    compute(2);
    asm volatile("s_waitcnt vmcnt(0)" ::: "memory");
    __builtin_amdgcn_s_barrier();
    asm volatile("" ::: "memory");
    compute(3);

#pragma unroll
    for (int m = 0; m < 4; m++)
#pragma unroll
        for (int n = 0; n < 4; n++)
#pragma unroll
            for (int r = 0; r < 4; r++) {
                int row = slot0 + wm*64 + m*16 + hi*4 + r;
                int col = col0 + wn*64 + n*16 + lr;
                float v = acc[m][n][r];
                if (e != NE) y2[(size_t)row * DIM + col] = f2bf(v);
                else         out[(size_t)(row - sbase) * DIM + col] = v + sb2[col];
            }
}

// --------- combine: out[n] += sum_k w_k * y2[slot_k(n)] ----------------------
__global__ void __launch_bounds__(256)
combine_kernel(const ushort* __restrict__ y2, const int* __restrict__ slots,
               const float* __restrict__ topk_w, float* __restrict__ out)
{
    __shared__ int ss[3];
    __shared__ float sw[3];
    const int n = blockIdx.x, tid = threadIdx.x;
    if (tid < 3) { ss[tid] = slots[n * 3 + tid]; sw[tid] = topk_w[n * 3 + tid]; }
    __syncthreads();
    float4* o4 = (float4*)(out + (size_t)n * DIM);
    float4 o = o4[tid];
#pragma unroll
    for (int k = 0; k < 3; k++) {
        const ushort4 yv = *(const ushort4*)(y2 + (size_t)ss[k] * DIM + tid * 4);
        float w = sw[k];
        o.x += w * bf2f(yv.x);
        o.y += w * bf2f(yv.y);
        o.z += w * bf2f(yv.z);
        o.w += w * bf2f(yv.w);
    }
    o4[tid] = o;
}

extern "C" void kernel_launch(void* const* d_in, const int* in_sizes, int n_in,
                              void* d_out, int out_size, void* d_ws, size_t ws_size,
                              hipStream_t stream)
{
    const float* x    = (const float*)d_in[0];
    const float* gw   = (const float*)d_in[1];
    const float* gb   = (const float*)d_in[2];
    const float* bia  = (const float*)d_in[3];
    const float* w1   = (const float*)d_in[4];
    const float* wg   = (const float*)d_in[5];
    const float* w2   = (const float*)d_in[6];
    const float* sw1  = (const float*)d_in[7];
    const float* sb1  = (const float*)d_in[8];
    const float* sw2  = (const float*)d_in[9];
    const float* sb2  = (const float*)d_in[10];
    float* out = (float*)d_out;

    // Workspace layout (bytes); total 173,452,288 <= proven ws_size >= 186,625,024.
    char* ws = (char*)d_ws;
    int*    ctrl   = (int*)   (ws + 0);          // [0]=ntiles [1]=rows [2]=shared_base, +8 counts, +16 cursors, +32 tiles
    int*    topk_e = (int*)   (ws + 4096);       //  98,304
    float*  topk_w = (float*) (ws + 102400);     //  98,304
    int*    slots  = (int*)   (ws + 200704);     //  98,304
    int*    row_tok= (int*)   (ws + 299008);     // 138,240 (34560 ints) -> pad to 437,248
    ushort* w1T    = (ushort*)(ws + 437248);     // 8 x 2MB (e7 = sw1T)
    ushort* wgT    = (ushort*)(ws + 17214464);   // 7 x 2MB
    ushort* w2T    = (ushort*)(ws + 31894528);   // 8 x 2MB (e7 = sw2T)
    ushort* h1     = (ushort*)(ws + 48671744);   // 34560 x 1024 bf16 = 70,778,880
    ushort* y2     = (ushort*)(ws + 119450624);  // 26368 x 1024 bf16 = 54,001,664 -> end 173,452,288
    ushort* xb     = y2;                         // alias: xb dead before g2 writes y2

    hipMemsetAsync(ctrl, 0, 4096, stream);
    transpose_convert<<<dim3(32, 32, 23), 256, 0, stream>>>(w1, wg, w2, sw1, sw2,
                                                            w1T, wgT, w2T);
    gate_kernel<<<N_TOK / 16, 256, 0, stream>>>(x, gw, gb, bia, topk_e, topk_w,
                                                ctrl + 8, xb);
    setup_kernel<<<1, 64, 0, stream>>>(ctrl, row_tok);
    ident_kernel<<<N_TOK / 256, 256, 0, stream>>>(ctrl, row_tok);
    scatter_kernel<<<N_TOK / 256, 256, 0, stream>>>(topk_e, topk_w, ctrl, row_tok,
                                                    slots);

    g1_kernel<<<dim3(MT_TILES, 8), 512, 0, stream>>>(xb, w1T, wgT, sb1, h1,
                                                     row_tok, ctrl);
    g2_kernel<<<dim3(MT_TILES, 8), 512, 0, stream>>>(h1, w2T, sb2, out, y2, ctrl);
    combine_kernel<<<N_TOK, 256, 0, stream>>>(y2, slots, topk_w, out);
}

// Round 7
// 476.071 us; speedup vs baseline: 2.0545x; 1.0023x over previous
//
#include <hip/hip_runtime.h>
#include <hip/hip_bf16.h>

// DeepSeekMoE: B=4,S=2048,D=1024,H=1024,E=7,NS=1,topk=3. N=8192 tokens.
#define N_TOK 8192
#define DIM   1024
#define NE    7
#define MT_TILES 136   // <= 103 routed tiles + 32 shared + slack; 136*8 % 8 == 0

typedef __attribute__((ext_vector_type(8))) short bf16x8;
typedef __attribute__((ext_vector_type(4))) float f32x4;

typedef __attribute__((address_space(3))) ushort lds_us_t;
typedef __attribute__((address_space(1))) const ushort glb_us_t;

__device__ __forceinline__ void gll16(const ushort* g, ushort* l) {
    __builtin_amdgcn_global_load_lds((glb_us_t*)g, (lds_us_t*)l, 16, 0, 0);
}

__device__ __forceinline__ unsigned short f2bf(float f) {
    unsigned int u = __builtin_bit_cast(unsigned int, f);
    u += 0x7fffu + ((u >> 16) & 1u);   // RNE
    return (unsigned short)(u >> 16);
}

__device__ __forceinline__ float bf2f(unsigned short b) {
    unsigned int u = ((unsigned int)b) << 16;
    return __builtin_bit_cast(float, u);
}

__device__ __forceinline__ float siluf(float v) { return v / (1.f + __expf(-v)); }

// ---------------- gate: logits -> softmax -> top3 -> renorm weights ----------
// Fuses x fp32->bf16 conversion.
__global__ void __launch_bounds__(256)
gate_kernel(const float* __restrict__ x, const float* __restrict__ gw,
            const float* __restrict__ gb, const float* __restrict__ bia,
            int* __restrict__ topk_e, float* __restrict__ topk_w,
            int* __restrict__ counts, ushort* __restrict__ xb)
{
    __shared__ float gwT[NE][DIM];   // 28 KB
    __shared__ int cnt[NE];
    const int tid = threadIdx.x;
    if (tid < NE) cnt[tid] = 0;
    for (int t = tid; t < NE * DIM; t += 256) {
        int d = t / NE, e = t - d * NE;
        gwT[e][d] = gw[t];
    }
    __syncthreads();

    const int lane = tid & 63, wid = tid >> 6;
#pragma unroll
    for (int tt = 0; tt < 4; tt++) {
        const int n = blockIdx.x * 16 + wid * 4 + tt;
        const float4* xr = (const float4*)(x + (size_t)n * DIM);
        ushort4* xo = (ushort4*)(xb + (size_t)n * DIM);
        float p[NE];
#pragma unroll
        for (int e = 0; e < NE; e++) p[e] = 0.f;
#pragma unroll
        for (int it = 0; it < 4; it++) {
            int i4 = it * 64 + lane;
            float4 v = xr[i4];
            ushort4 o;
            o.x = f2bf(v.x); o.y = f2bf(v.y); o.z = f2bf(v.z); o.w = f2bf(v.w);
            xo[i4] = o;
            int d = i4 * 4;
#pragma unroll
            for (int e = 0; e < NE; e++) {
                float4 g = *(const float4*)&gwT[e][d];
                p[e] += v.x * g.x + v.y * g.y + v.z * g.z + v.w * g.w;
            }
        }
#pragma unroll
        for (int e = 0; e < NE; e++)
            for (int off = 32; off; off >>= 1) p[e] += __shfl_xor(p[e], off);
        if (lane == 0) {
            float l[NE], m = -1e30f;
#pragma unroll
            for (int e = 0; e < NE; e++) { l[e] = p[e] + gb[e]; m = fmaxf(m, l[e]); }
            float s = 0.f;
#pragma unroll
            for (int e = 0; e < NE; e++) { l[e] = __expf(l[e] - m); s += l[e]; }
            float inv = 1.f / s;
#pragma unroll
            for (int e = 0; e < NE; e++) l[e] *= inv;          // probs
            float adj[NE]; bool used[NE];
#pragma unroll
            for (int e = 0; e < NE; e++) { adj[e] = l[e] + bia[e]; used[e] = false; }
            int sel[3]; float w[3]; float ws = 0.f;
            for (int k = 0; k < 3; k++) {
                int b = -1; float bv = -1e30f;
                for (int e = 0; e < NE; e++)
                    if (!used[e] && adj[e] > bv) { bv = adj[e]; b = e; }
                used[b] = true; sel[k] = b; w[k] = l[b]; ws += w[k];
            }
            float iws = 1.f / ws;
            for (int k = 0; k < 3; k++) {
                topk_e[n * 3 + k] = sel[k];
                topk_w[n * 3 + k] = w[k] * iws;
                atomicAdd(&cnt[sel[k]], 1);
            }
        }
    }
    __syncthreads();
    if (tid < NE) atomicAdd(&counts[tid], cnt[tid]);
}

// --------- setup (1 thread): 256-pad scan + tile list (pads memset'd) --------
__global__ void setup_kernel(int* __restrict__ ctrl)
{
    if (threadIdx.x != 0 || blockIdx.x != 0) return;
    int* counts = ctrl + 8; int* cursors = ctrl + 16; int* tiles = ctrl + 32;
    int nm = 0, off = 0;
    for (int e = 0; e < NE; e++) {
        int c = counts[e];
        int padc = (c + 255) & ~255;
        cursors[e] = off;
        for (int t = 0; t < padc; t += 256) { tiles[nm*2] = e; tiles[nm*2+1] = off + t; nm++; }
        off += padc;
    }
    ctrl[2] = off;                       // shared_base
    for (int t = 0; t < N_TOK; t += 256) { tiles[nm*2] = NE; tiles[nm*2+1] = off + t; nm++; }
    ctrl[1] = off + N_TOK;               // total rows
    ctrl[0] = nm;                        // tile count
}

// --------- identity fill for shared region -----------------------------------
__global__ void ident_kernel(const int* __restrict__ ctrl, int* __restrict__ row_tok)
{
    int n = blockIdx.x * 256 + threadIdx.x;
    row_tok[ctrl[2] + n] = n;
}

// --------- scatter: token -> per-expert padded slots (+ inverse map) ---------
__global__ void scatter_kernel(const int* __restrict__ topk_e, const float* __restrict__ topk_w,
                               int* __restrict__ ctrl, int* __restrict__ row_tok,
                               int* __restrict__ slots)
{
    int n = blockIdx.x * blockDim.x + threadIdx.x;
    if (n >= N_TOK) return;
    int* cursors = ctrl + 16;
    for (int k = 0; k < 3; k++) {
        int e = topk_e[n * 3 + k];
        int slot = atomicAdd(&cursors[e], 1);
        row_tok[slot] = n;
        slots[n * 3 + k] = slot;
    }
}

// --------- transpose+convert weights to B^T bf16 -----------------------------
__global__ void transpose_convert(const float* __restrict__ w1, const float* __restrict__ wg,
                                  const float* __restrict__ w2, const float* __restrict__ sw1,
                                  const float* __restrict__ sw2,
                                  ushort* __restrict__ w1T, ushort* __restrict__ wgT,
                                  ushort* __restrict__ w2T)
{
    int z = blockIdx.z;
    const float* src; ushort* dst;
    if (z < 7)       { src = w1 + (size_t)z * (DIM*DIM);        dst = w1T + (size_t)z * (DIM*DIM); }
    else if (z < 14) { src = wg + (size_t)(z - 7) * (DIM*DIM);  dst = wgT + (size_t)(z - 7) * (DIM*DIM); }
    else if (z < 21) { src = w2 + (size_t)(z - 14) * (DIM*DIM); dst = w2T + (size_t)(z - 14) * (DIM*DIM); }
    else if (z == 21){ src = sw1; dst = w1T + (size_t)NE * (DIM*DIM); }
    else             { src = sw2; dst = w2T + (size_t)NE * (DIM*DIM); }
    __shared__ float t[32][33];
    int bx = blockIdx.x * 32, by = blockIdx.y * 32;
    int lx = threadIdx.x & 31, ly = threadIdx.x >> 5;
#pragma unroll
    for (int i = 0; i < 32; i += 8)
        t[ly + i][lx] = src[(size_t)(by + ly + i) * DIM + bx + lx];
    __syncthreads();
#pragma unroll
    for (int i = 0; i < 32; i += 8) {
        int r = ly + i;
        dst[(size_t)(bx + r) * DIM + by + lx] = f2bf(t[lx][r]);
    }
}

// XCD-aware remap: XCD k owns x-tiles [17k,17k+17) x all 8 col-blocks.
// L = hw linear block id (round-robin xcd = L&7); bijective since 1088%8==0.
__device__ __forceinline__ void xcd_remap(int& bx, int& col0) {
    int L = blockIdx.x + blockIdx.y * MT_TILES;
    int D = (L & 7) * MT_TILES + (L >> 3);
    bx = D >> 3;
    col0 = (D & 7) * 128;
}

// ============ deep-pipelined GEMM: BM=256 BN=128 BK=32 =======================
// Dual-row packed LDS: (row r, k-chunk c) at ushort
//   (r>>1)*64 + (((((r&1)<<2)|c) ^ ((r>>1)&7))*8,  c = k/8 in 0..3.
// global_load_lds writes linearly; source address inverse-swizzled (rule #21).
// 2 lanes/bank on ds_read_b128 (free). Stage t+2 while computing t.

// ---- G1: h = silu(x@w1)*(x@wg)  (e<7)  |  silu(x@sw1 + sb1)  (e==7) ---------
__global__ void __launch_bounds__(512, 2)
g1_kernel(const ushort* __restrict__ Xb, const ushort* __restrict__ W1,
          const ushort* __restrict__ WG, const float* __restrict__ sb1,
          ushort* __restrict__ H, const int* __restrict__ row_tok,
          const int* __restrict__ ctrl)
{
    __shared__ ushort lds[65536];   // 128 KB: 4 bufs x (8192 A + 4096 B1 + 4096 B2)
    int bx, col0;
    xcd_remap(bx, col0);
    if (bx >= ctrl[0]) return;
    const int e     = ctrl[32 + 2*bx];
    const int slot0 = ctrl[32 + 2*bx + 1];
    const bool gated = (e != NE);
    const int tt = threadIdx.x;
    const int lane = tt & 63, wid = tt >> 6;
    const int wm = wid >> 1, wn = wid & 1;
    const int wofs = wid * 512;

    // staging source (inverse-swizzled global address)
    const int slog = (tt & 7) ^ ((tt >> 3) & 7);
    const int kk0 = (slog & 3) * 8;
    const int r0 = ((tt >> 3) << 1) + (slog >> 2);
    const ushort* pA0 = Xb + (size_t)row_tok[slot0 + r0] * DIM + kk0;
    const ushort* pA1 = Xb + (size_t)row_tok[slot0 + r0 + 128] * DIM + kk0;
    const ushort* B1e = W1 + (size_t)e * (DIM*DIM);
    const ushort* B2e = gated ? (WG + (size_t)e * (DIM*DIM))
                              : (W1 + (size_t)NE * (DIM*DIM));
    const ushort* pB1 = B1e + (size_t)(col0 + r0) * DIM + kk0;
    const ushort* pB2 = B2e + (size_t)(col0 + r0) * DIM + kk0;

    // fragment read offsets (swizzled)
    const int hi = lane >> 4, lr = lane & 15;
    int aoff[4], boff[4];
#pragma unroll
    for (int m = 0; m < 4; m++) {
        int row = wm*64 + m*16 + lr;
        int lrow = row >> 1;
        int sl = ((row & 1) << 2) | hi;
        aoff[m] = lrow*64 + (sl ^ (lrow & 7))*8;
    }
#pragma unroll
    for (int n = 0; n < 4; n++) {
        int oc = wn*64 + n*16 + lr;
        int lrow = oc >> 1;
        int sl = ((oc & 1) << 2) | hi;
        boff[n] = lrow*64 + (sl ^ (lrow & 7))*8;
    }

    f32x4 zero4 = {0.f, 0.f, 0.f, 0.f};
    f32x4 acc1[4][4], acc2[4][4];
#pragma unroll
    for (int m = 0; m < 4; m++)
#pragma unroll
        for (int n = 0; n < 4; n++) { acc1[m][n] = zero4; acc2[m][n] = zero4; }

    auto stage = [&](int buf, int kte) {
        ushort* b = &lds[buf * 16384];
        gll16(pA0 + kte, b + wofs);
        gll16(pA1 + kte, b + 4096 + wofs);
        gll16(pB1 + kte, b + 8192 + wofs);
        gll16(pB2 + kte, b + 12288 + wofs);
    };
    auto compute = [&](int buf) {
        const ushort* Ab = &lds[buf * 16384];
        const ushort* Bb = Ab + 8192;
        bf16x8 a[4], bv[4];
#pragma unroll
        for (int m = 0; m < 4; m++) a[m] = *(const bf16x8*)(Ab + aoff[m]);
#pragma unroll
        for (int n = 0; n < 4; n++) bv[n] = *(const bf16x8*)(Bb + boff[n]);
        __builtin_amdgcn_s_setprio(1);
#pragma unroll
        for (int m = 0; m < 4; m++)
#pragma unroll
            for (int n = 0; n < 4; n++)
                acc1[m][n] = __builtin_amdgcn_mfma_f32_16x16x32_bf16(a[m], bv[n], acc1[m][n], 0, 0, 0);
        __builtin_amdgcn_s_setprio(0);
        if (gated) {
            const ushort* B2b = Ab + 12288;
            bf16x8 b2[4];
#pragma unroll
            for (int n = 0; n < 4; n++) b2[n] = *(const bf16x8*)(B2b + boff[n]);
            __builtin_amdgcn_s_setprio(1);
#pragma unroll
            for (int m = 0; m < 4; m++)
#pragma unroll
                for (int n = 0; n < 4; n++)
                    acc2[m][n] = __builtin_amdgcn_mfma_f32_16x16x32_bf16(a[m], b2[n], acc2[m][n], 0, 0, 0);
            __builtin_amdgcn_s_setprio(0);
        }
    };

    stage(0, 0); stage(1, 32);
    asm volatile("s_waitcnt vmcnt(4)" ::: "memory");
    __builtin_amdgcn_s_barrier();
    asm volatile("" ::: "memory");
    for (int t = 0; t < 30; ++t) {
        stage((t + 2) & 3, (t + 2) * 32);
        compute(t & 3);
        asm volatile("s_waitcnt vmcnt(4)" ::: "memory");
        __builtin_amdgcn_s_barrier();
        asm volatile("" ::: "memory");
    }
    compute(2);
    asm volatile("s_waitcnt vmcnt(0)" ::: "memory");
    __builtin_amdgcn_s_barrier();
    asm volatile("" ::: "memory");
    compute(3);

    // epilogue: SwiGLU (routed) / bias-silu (shared)
#pragma unroll
    for (int m = 0; m < 4; m++)
#pragma unroll
        for (int n = 0; n < 4; n++)
#pragma unroll
            for (int r = 0; r < 4; r++) {
                int row = slot0 + wm*64 + m*16 + hi*4 + r;
                int col = col0 + wn*64 + n*16 + lr;
                float v1 = acc1[m][n][r];
                float h = gated ? siluf(v1) * acc2[m][n][r]
                                : siluf(v1 + sb1[col]);
                H[(size_t)row * DIM + col] = f2bf(h);
            }
}

// ---- G2: y = h @ w2 ; routed -> y2 bf16 ; shared -> out = y + sb2 (fp32) ----
// Triple-buffered (72 KB LDS) -> 2 blocks/CU for cross-block latency hiding.
__global__ void __launch_bounds__(512, 2)
g2_kernel(const ushort* __restrict__ H, const ushort* __restrict__ W2,
          const float* __restrict__ sb2, float* __restrict__ out,
          ushort* __restrict__ y2, const int* __restrict__ ctrl)
{
    __shared__ ushort lds[36864];   // 72 KB: 3 bufs x (8192 A + 4096 B)
    int bx, col0;
    xcd_remap(bx, col0);
    if (bx >= ctrl[0]) return;
    const int e     = ctrl[32 + 2*bx];
    const int slot0 = ctrl[32 + 2*bx + 1];
    const int sbase = ctrl[2];
    const int tt = threadIdx.x;
    const int lane = tt & 63, wid = tt >> 6;
    const int wm = wid >> 1, wn = wid & 1;
    const int wofs = wid * 512;

    const int slog = (tt & 7) ^ ((tt >> 3) & 7);
    const int kk0 = (slog & 3) * 8;
    const int r0 = ((tt >> 3) << 1) + (slog >> 2);
    const ushort* pA0 = H + (size_t)(slot0 + r0) * DIM + kk0;
    const ushort* pA1 = H + (size_t)(slot0 + r0 + 128) * DIM + kk0;
    const ushort* Be  = W2 + (size_t)e * (DIM*DIM);
    const ushort* pB1 = Be + (size_t)(col0 + r0) * DIM + kk0;

    const int hi = lane >> 4, lr = lane & 15;
    int aoff[4], boff[4];
#pragma unroll
    for (int m = 0; m < 4; m++) {
        int row = wm*64 + m*16 + lr;
        int lrow = row >> 1;
        int sl = ((row & 1) << 2) | hi;
        aoff[m] = lrow*64 + (sl ^ (lrow & 7))*8;
    }
#pragma unroll
    for (int n = 0; n < 4; n++) {
        int oc = wn*64 + n*16 + lr;
        int lrow = oc >> 1;
        int sl = ((oc & 1) << 2) | hi;
        boff[n] = lrow*64 + (sl ^ (lrow & 7))*8;
    }

    f32x4 zero4 = {0.f, 0.f, 0.f, 0.f};
    f32x4 acc[4][4];
#pragma unroll
    for (int m = 0; m < 4; m++)
#pragma unroll
        for (int n = 0; n < 4; n++) acc[m][n] = zero4;

    auto stage = [&](int buf, int kte) {
        ushort* b = &lds[buf * 12288];
        gll16(pA0 + kte, b + wofs);
        gll16(pA1 + kte, b + 4096 + wofs);
        gll16(pB1 + kte, b + 8192 + wofs);
    };
    auto compute = [&](int buf) {
        const ushort* Ab = &lds[buf * 12288];
        const ushort* Bb = Ab + 8192;
        bf16x8 a[4], bv[4];
#pragma unroll
        for (int m = 0; m < 4; m++) a[m] = *(const bf16x8*)(Ab + aoff[m]);
#pragma unroll
        for (int n = 0; n < 4; n++) bv[n] = *(const bf16x8*)(Bb + boff[n]);
        __builtin_amdgcn_s_setprio(1);
#pragma unroll
        for (int m = 0; m < 4; m++)
#pragma unroll
            for (int n = 0; n < 4; n++)
                acc[m][n] = __builtin_amdgcn_mfma_f32_16x16x32_bf16(a[m], bv[n], acc[m][n], 0, 0, 0);
        __builtin_amdgcn_s_setprio(0);
    };

    stage(0, 0); stage(1, 32);
    asm volatile("s_waitcnt vmcnt(3)" ::: "memory");
    __builtin_amdgcn_s_barrier();
    asm volatile("" ::: "memory");
    int sbuf = 2, cbuf = 0;          // rotating mod-3 counters (r6 bug: folded %3 was wrong)
    for (int t = 0; t < 30; ++t) {
        stage(sbuf, (t + 2) * 32);
        compute(cbuf);
        asm volatile("s_waitcnt vmcnt(3)" ::: "memory");
        __builtin_amdgcn_s_barrier();
        asm volatile("" ::: "memory");
        sbuf = (sbuf == 2) ? 0 : sbuf + 1;
        cbuf = (cbuf == 2) ? 0 : cbuf + 1;
    }
    compute(cbuf);                    // tile 30 -> buf 0
    asm volatile("s_waitcnt vmcnt(0)" ::: "memory");
    __builtin_amdgcn_s_barrier();
    asm volatile("" ::: "memory");
    cbuf = (cbuf == 2) ? 0 : cbuf + 1;
    compute(cbuf);                    // tile 31 -> buf 1

#pragma unroll
    for (int m = 0; m < 4; m++)
#pragma unroll
        for (int n = 0; n < 4; n++)
#pragma unroll
            for (int r = 0; r < 4; r++) {
                int row = slot0 + wm*64 + m*16 + hi*4 + r;
                int col = col0 + wn*64 + n*16 + lr;
                float v = acc[m][n][r];
                if (e != NE) y2[(size_t)row * DIM + col] = f2bf(v);
                else         out[(size_t)(row - sbase) * DIM + col] = v + sb2[col];
            }
}

// --------- combine: out[n] += sum_k w_k * y2[slot_k(n)] ----------------------
__global__ void __launch_bounds__(256)
combine_kernel(const ushort* __restrict__ y2, const int* __restrict__ slots,
               const float* __restrict__ topk_w, float* __restrict__ out)
{
    __shared__ int ss[3];
    __shared__ float sw[3];
    const int n = blockIdx.x, tid = threadIdx.x;
    if (tid < 3) { ss[tid] = slots[n * 3 + tid]; sw[tid] = topk_w[n * 3 + tid]; }
    __syncthreads();
    float4* o4 = (float4*)(out + (size_t)n * DIM);
    float4 o = o4[tid];
#pragma unroll
    for (int k = 0; k < 3; k++) {
        const ushort4 yv = *(const ushort4*)(y2 + (size_t)ss[k] * DIM + tid * 4);
        float w = sw[k];
        o.x += w * bf2f(yv.x);
        o.y += w * bf2f(yv.y);
        o.z += w * bf2f(yv.z);
        o.w += w * bf2f(yv.w);
    }
    o4[tid] = o;
}

extern "C" void kernel_launch(void* const* d_in, const int* in_sizes, int n_in,
                              void* d_out, int out_size, void* d_ws, size_t ws_size,
                              hipStream_t stream)
{
    const float* x    = (const float*)d_in[0];
    const float* gw   = (const float*)d_in[1];
    const float* gb   = (const float*)d_in[2];
    const float* bia  = (const float*)d_in[3];
    const float* w1   = (const float*)d_in[4];
    const float* wg   = (const float*)d_in[5];
    const float* w2   = (const float*)d_in[6];
    const float* sw1  = (const float*)d_in[7];
    const float* sb1  = (const float*)d_in[8];
    const float* sw2  = (const float*)d_in[9];
    const float* sb2  = (const float*)d_in[10];
    float* out = (float*)d_out;

    // Workspace layout (bytes); total 173,452,288 <= proven ws_size >= 186,625,024.
    char* ws = (char*)d_ws;
    int*    ctrl   = (int*)   (ws + 0);          // [0]=ntiles [1]=rows [2]=shared_base, +8 counts, +16 cursors, +32 tiles
    int*    topk_e = (int*)   (ws + 4096);       //  98,304
    float*  topk_w = (float*) (ws + 102400);     //  98,304
    int*    slots  = (int*)   (ws + 200704);     //  98,304
    int*    row_tok= (int*)   (ws + 299008);     // 138,240 (34560 ints) -> pad to 437,248
    ushort* w1T    = (ushort*)(ws + 437248);     // 8 x 2MB (e7 = sw1T)
    ushort* wgT    = (ushort*)(ws + 17214464);   // 7 x 2MB
    ushort* w2T    = (ushort*)(ws + 31894528);   // 8 x 2MB (e7 = sw2T)
    ushort* h1     = (ushort*)(ws + 48671744);   // 34560 x 1024 bf16 = 70,778,880
    ushort* y2     = (ushort*)(ws + 119450624);  // 26368 x 1024 bf16 = 54,001,664 -> end 173,452,288
    ushort* xb     = y2;                         // alias: xb dead before g2 writes y2

    hipMemsetAsync(ctrl, 0, 4096, stream);
    hipMemsetAsync(row_tok, 0, 34560 * 4, stream);   // pad slots default to token 0
    transpose_convert<<<dim3(32, 32, 23), 256, 0, stream>>>(w1, wg, w2, sw1, sw2,
                                                            w1T, wgT, w2T);
    gate_kernel<<<N_TOK / 16, 256, 0, stream>>>(x, gw, gb, bia, topk_e, topk_w,
                                                ctrl + 8, xb);
    setup_kernel<<<1, 64, 0, stream>>>(ctrl);
    ident_kernel<<<N_TOK / 256, 256, 0, stream>>>(ctrl, row_tok);
    scatter_kernel<<<N_TOK / 256, 256, 0, stream>>>(topk_e, topk_w, ctrl, row_tok,
                                                    slots);

    g1_kernel<<<dim3(MT_TILES, 8), 512, 0, stream>>>(xb, w1T, wgT, sb1, h1,
                                                     row_tok, ctrl);
    g2_kernel<<<dim3(MT_TILES, 8), 512, 0, stream>>>(h1, w2T, sb2, out, y2, ctrl);
    combine_kernel<<<N_TOK, 256, 0, stream>>>(y2, slots, topk_w, out);
}

// Round 8
// 473.456 us; speedup vs baseline: 2.0658x; 1.0055x over previous
//
#include <hip/hip_runtime.h>
#include <hip/hip_bf16.h>

// DeepSeekMoE: B=4,S=2048,D=1024,H=1024,E=7,NS=1,topk=3. N=8192 tokens.
#define N_TOK 8192
#define DIM   1024
#define NE    7
#define MT_TILES 136   // <= ~103 routed tiles + 32 shared + slack; 136*8 % 8 == 0

typedef __attribute__((ext_vector_type(8))) short bf16x8;
typedef __attribute__((ext_vector_type(4))) float f32x4;

typedef __attribute__((address_space(3))) ushort lds_us_t;
typedef __attribute__((address_space(1))) const ushort glb_us_t;

__device__ __forceinline__ void gll16(const ushort* g, ushort* l) {
    __builtin_amdgcn_global_load_lds((glb_us_t*)g, (lds_us_t*)l, 16, 0, 0);
}

__device__ __forceinline__ unsigned short f2bf(float f) {
    unsigned int u = __builtin_bit_cast(unsigned int, f);
    u += 0x7fffu + ((u >> 16) & 1u);   // RNE
    return (unsigned short)(u >> 16);
}

__device__ __forceinline__ float bf2f(unsigned short b) {
    unsigned int u = ((unsigned int)b) << 16;
    return __builtin_bit_cast(float, u);
}

__device__ __forceinline__ float siluf(float v) { return v / (1.f + __expf(-v)); }

// ---------------- gate: logits -> softmax -> top3 -> renorm weights ----------
// Fuses x fp32->bf16 conversion.
__global__ void __launch_bounds__(256)
gate_kernel(const float* __restrict__ x, const float* __restrict__ gw,
            const float* __restrict__ gb, const float* __restrict__ bia,
            int* __restrict__ topk_e, float* __restrict__ topk_w,
            int* __restrict__ counts, ushort* __restrict__ xb)
{
    __shared__ float gwT[NE][DIM];   // 28 KB
    __shared__ int cnt[NE];
    const int tid = threadIdx.x;
    if (tid < NE) cnt[tid] = 0;
    for (int t = tid; t < NE * DIM; t += 256) {
        int d = t / NE, e = t - d * NE;
        gwT[e][d] = gw[t];
    }
    __syncthreads();

    const int lane = tid & 63, wid = tid >> 6;
#pragma unroll
    for (int tt = 0; tt < 4; tt++) {
        const int n = blockIdx.x * 16 + wid * 4 + tt;
        const float4* xr = (const float4*)(x + (size_t)n * DIM);
        ushort4* xo = (ushort4*)(xb + (size_t)n * DIM);
        float p[NE];
#pragma unroll
        for (int e = 0; e < NE; e++) p[e] = 0.f;
#pragma unroll
        for (int it = 0; it < 4; it++) {
            int i4 = it * 64 + lane;
            float4 v = xr[i4];
            ushort4 o;
            o.x = f2bf(v.x); o.y = f2bf(v.y); o.z = f2bf(v.z); o.w = f2bf(v.w);
            xo[i4] = o;
            int d = i4 * 4;
#pragma unroll
            for (int e = 0; e < NE; e++) {
                float4 g = *(const float4*)&gwT[e][d];
                p[e] += v.x * g.x + v.y * g.y + v.z * g.z + v.w * g.w;
            }
        }
#pragma unroll
        for (int e = 0; e < NE; e++)
            for (int off = 32; off; off >>= 1) p[e] += __shfl_xor(p[e], off);
        if (lane == 0) {
            float l[NE], m = -1e30f;
#pragma unroll
            for (int e = 0; e < NE; e++) { l[e] = p[e] + gb[e]; m = fmaxf(m, l[e]); }
            float s = 0.f;
#pragma unroll
            for (int e = 0; e < NE; e++) { l[e] = __expf(l[e] - m); s += l[e]; }
            float inv = 1.f / s;
#pragma unroll
            for (int e = 0; e < NE; e++) l[e] *= inv;          // probs
            float adj[NE]; bool used[NE];
#pragma unroll
            for (int e = 0; e < NE; e++) { adj[e] = l[e] + bia[e]; used[e] = false; }
            int sel[3]; float w[3]; float ws = 0.f;
            for (int k = 0; k < 3; k++) {
                int b = -1; float bv = -1e30f;
                for (int e = 0; e < NE; e++)
                    if (!used[e] && adj[e] > bv) { bv = adj[e]; b = e; }
                used[b] = true; sel[k] = b; w[k] = l[b]; ws += w[k];
            }
            float iws = 1.f / ws;
            for (int k = 0; k < 3; k++) {
                topk_e[n * 3 + k] = sel[k];
                topk_w[n * 3 + k] = w[k] * iws;
                atomicAdd(&cnt[sel[k]], 1);
            }
        }
    }
    __syncthreads();
    if (tid < NE) atomicAdd(&counts[tid], cnt[tid]);
}

// --------- setup (1 thread): 256-pad scan + tile list (pads memset'd) --------
__global__ void setup_kernel(int* __restrict__ ctrl)
{
    if (threadIdx.x != 0 || blockIdx.x != 0) return;
    int* counts = ctrl + 8; int* cursors = ctrl + 16; int* tiles = ctrl + 32;
    int nm = 0, off = 0;
    for (int e = 0; e < NE; e++) {
        int c = counts[e];
        int padc = (c + 255) & ~255;
        cursors[e] = off;
        for (int t = 0; t < padc; t += 256) { tiles[nm*2] = e; tiles[nm*2+1] = off + t; nm++; }
        off += padc;
    }
    ctrl[2] = off;                       // shared_base
    for (int t = 0; t < N_TOK; t += 256) { tiles[nm*2] = NE; tiles[nm*2+1] = off + t; nm++; }
    ctrl[1] = off + N_TOK;               // total rows
    ctrl[0] = nm;                        // tile count
}

// --------- identity fill for shared region -----------------------------------
__global__ void ident_kernel(const int* __restrict__ ctrl, int* __restrict__ row_tok)
{
    int n = blockIdx.x * 256 + threadIdx.x;
    row_tok[ctrl[2] + n] = n;
}

// --------- scatter: token -> per-expert padded slots (+ inverse map) ---------
__global__ void scatter_kernel(const int* __restrict__ topk_e, const float* __restrict__ topk_w,
                               int* __restrict__ ctrl, int* __restrict__ row_tok,
                               int* __restrict__ slots)
{
    int n = blockIdx.x * blockDim.x + threadIdx.x;
    if (n >= N_TOK) return;
    int* cursors = ctrl + 16;
    for (int k = 0; k < 3; k++) {
        int e = topk_e[n * 3 + k];
        int slot = atomicAdd(&cursors[e], 1);
        row_tok[slot] = n;
        slots[n * 3 + k] = slot;
    }
}

// --------- transpose+convert weights to B^T bf16 -----------------------------
__global__ void transpose_convert(const float* __restrict__ w1, const float* __restrict__ wg,
                                  const float* __restrict__ w2, const float* __restrict__ sw1,
                                  const float* __restrict__ sw2,
                                  ushort* __restrict__ w1T, ushort* __restrict__ wgT,
                                  ushort* __restrict__ w2T)
{
    int z = blockIdx.z;
    const float* src; ushort* dst;
    if (z < 7)       { src = w1 + (size_t)z * (DIM*DIM);        dst = w1T + (size_t)z * (DIM*DIM); }
    else if (z < 14) { src = wg + (size_t)(z - 7) * (DIM*DIM);  dst = wgT + (size_t)(z - 7) * (DIM*DIM); }
    else if (z < 21) { src = w2 + (size_t)(z - 14) * (DIM*DIM); dst = w2T + (size_t)(z - 14) * (DIM*DIM); }
    else if (z == 21){ src = sw1; dst = w1T + (size_t)NE * (DIM*DIM); }
    else             { src = sw2; dst = w2T + (size_t)NE * (DIM*DIM); }
    __shared__ float t[32][33];
    int bx = blockIdx.x * 32, by = blockIdx.y * 32;
    int lx = threadIdx.x & 31, ly = threadIdx.x >> 5;
#pragma unroll
    for (int i = 0; i < 32; i += 8)
        t[ly + i][lx] = src[(size_t)(by + ly + i) * DIM + bx + lx];
    __syncthreads();
#pragma unroll
    for (int i = 0; i < 32; i += 8) {
        int r = ly + i;
        dst[(size_t)(bx + r) * DIM + by + lx] = f2bf(t[lx][r]);
    }
}

// XCD-aware remap: XCD k owns x-tiles [17k,17k+17) x all 8 col-blocks.
__device__ __forceinline__ void xcd_remap(int& bx, int& col0) {
    int L = blockIdx.x + blockIdx.y * MT_TILES;
    int D = (L & 7) * MT_TILES + (L >> 3);
    bx = D >> 3;
    col0 = (D & 7) * 128;
}

// ============ deep-pipelined GEMM: BM=256 BN=128 BK=32, quad-buffer ==========
// Dual-row packed LDS swizzle (2 lanes/bank, free); gll16 linear dest with
// inverse-swizzled global source (rule #21). Depth-3 prefetch: stage t+3
// during t, vmcnt leaves 2 tiles in flight (never 0 in the main loop).

// ---- G1: h = silu(x@w1)*(x@wg)  (e<7)  |  silu(x@sw1 + sb1)  (e==7) ---------
__global__ void __launch_bounds__(512, 2)
g1_kernel(const ushort* __restrict__ Xb, const ushort* __restrict__ W1,
          const ushort* __restrict__ WG, const float* __restrict__ sb1,
          ushort* __restrict__ H, const int* __restrict__ row_tok,
          const int* __restrict__ ctrl)
{
    __shared__ ushort lds[65536];   // 128 KB: 4 bufs x (8192 A + 4096 B1 + 4096 B2)
    int bx, col0;
    xcd_remap(bx, col0);
    if (bx >= ctrl[0]) return;
    const int e     = ctrl[32 + 2*bx];
    const int slot0 = ctrl[32 + 2*bx + 1];
    const bool gated = (e != NE);
    const int tt = threadIdx.x;
    const int lane = tt & 63, wid = tt >> 6;
    const int wm = wid >> 1, wn = wid & 1;
    const int wofs = wid * 512;

    // staging source (inverse-swizzled global address)
    const int slog = (tt & 7) ^ ((tt >> 3) & 7);
    const int kk0 = (slog & 3) * 8;
    const int r0 = ((tt >> 3) << 1) + (slog >> 2);
    const ushort* pA0 = Xb + (size_t)row_tok[slot0 + r0] * DIM + kk0;
    const ushort* pA1 = Xb + (size_t)row_tok[slot0 + r0 + 128] * DIM + kk0;
    const ushort* B1e = W1 + (size_t)e * (DIM*DIM);
    const ushort* B2e = gated ? (WG + (size_t)e * (DIM*DIM))
                              : (W1 + (size_t)NE * (DIM*DIM));
    const ushort* pB1 = B1e + (size_t)(col0 + r0) * DIM + kk0;
    const ushort* pB2 = B2e + (size_t)(col0 + r0) * DIM + kk0;

    // fragment read offsets (swizzled)
    const int hi = lane >> 4, lr = lane & 15;
    int aoff[4], boff[4];
#pragma unroll
    for (int m = 0; m < 4; m++) {
        int row = wm*64 + m*16 + lr;
        int lrow = row >> 1;
        int sl = ((row & 1) << 2) | hi;
        aoff[m] = lrow*64 + (sl ^ (lrow & 7))*8;
    }
#pragma unroll
    for (int n = 0; n < 4; n++) {
        int oc = wn*64 + n*16 + lr;
        int lrow = oc >> 1;
        int sl = ((oc & 1) << 2) | hi;
        boff[n] = lrow*64 + (sl ^ (lrow & 7))*8;
    }

    f32x4 zero4 = {0.f, 0.f, 0.f, 0.f};
    f32x4 acc1[4][4], acc2[4][4];
#pragma unroll
    for (int m = 0; m < 4; m++)
#pragma unroll
        for (int n = 0; n < 4; n++) { acc1[m][n] = zero4; acc2[m][n] = zero4; }

    auto stage = [&](int buf, int kte) {
        ushort* b = &lds[buf * 16384];
        gll16(pA0 + kte, b + wofs);
        gll16(pA1 + kte, b + 4096 + wofs);
        gll16(pB1 + kte, b + 8192 + wofs);
        gll16(pB2 + kte, b + 12288 + wofs);
    };
    auto compute = [&](int buf) {
        const ushort* Ab = &lds[buf * 16384];
        const ushort* Bb = Ab + 8192;
        bf16x8 a[4], bv[4];
#pragma unroll
        for (int m = 0; m < 4; m++) a[m] = *(const bf16x8*)(Ab + aoff[m]);
#pragma unroll
        for (int n = 0; n < 4; n++) bv[n] = *(const bf16x8*)(Bb + boff[n]);
        __builtin_amdgcn_s_setprio(1);
#pragma unroll
        for (int m = 0; m < 4; m++)
#pragma unroll
            for (int n = 0; n < 4; n++)
                acc1[m][n] = __builtin_amdgcn_mfma_f32_16x16x32_bf16(a[m], bv[n], acc1[m][n], 0, 0, 0);
        __builtin_amdgcn_s_setprio(0);
        if (gated) {
            const ushort* B2b = Ab + 12288;
            bf16x8 b2[4];
#pragma unroll
            for (int n = 0; n < 4; n++) b2[n] = *(const bf16x8*)(B2b + boff[n]);
            __builtin_amdgcn_s_setprio(1);
#pragma unroll
            for (int m = 0; m < 4; m++)
#pragma unroll
                for (int n = 0; n < 4; n++)
                    acc2[m][n] = __builtin_amdgcn_mfma_f32_16x16x32_bf16(a[m], b2[n], acc2[m][n], 0, 0, 0);
            __builtin_amdgcn_s_setprio(0);
        }
    };

    // depth-3 prefetch: buffers t, t+1 landed; t+2, t+3 in flight (vmcnt 8 = 2x4)
    stage(0, 0); stage(1, 32); stage(2, 64);
    asm volatile("s_waitcnt vmcnt(8)" ::: "memory");   // tile 0 landed
    __builtin_amdgcn_s_barrier();
    asm volatile("" ::: "memory");
    for (int t = 0; t < 29; ++t) {
        stage((t + 3) & 3, (t + 3) * 32);
        compute(t & 3);
        asm volatile("s_waitcnt vmcnt(8)" ::: "memory");  // t+1 landed; t+2,t+3 in flight
        __builtin_amdgcn_s_barrier();
        asm volatile("" ::: "memory");
    }
    compute(1);                                           // tile 29
    asm volatile("s_waitcnt vmcnt(4)" ::: "memory");      // tile 30 landed
    __builtin_amdgcn_s_barrier();
    asm volatile("" ::: "memory");
    compute(2);                                           // tile 30
    asm volatile("s_waitcnt vmcnt(0)" ::: "memory");      // tile 31 landed
    __builtin_amdgcn_s_barrier();
    asm volatile("" ::: "memory");
    compute(3);                                           // tile 31

    // epilogue: SwiGLU (routed) / bias-silu (shared)
#pragma unroll
    for (int m = 0; m < 4; m++)
#pragma unroll
        for (int n = 0; n < 4; n++)
#pragma unroll
            for (int r = 0; r < 4; r++) {
                int row = slot0 + wm*64 + m*16 + hi*4 + r;
                int col = col0 + wn*64 + n*16 + lr;
                float v1 = acc1[m][n][r];
                float h = gated ? siluf(v1) * acc2[m][n][r]
                                : siluf(v1 + sb1[col]);
                H[(size_t)row * DIM + col] = f2bf(h);
            }
}

// ---- G2: y = h @ w2 ; routed -> y2 bf16 ; shared -> out = y + sb2 (fp32) ----
// Quad-buffer (96 KB), depth-3 prefetch (vmcnt 6 = 2 tiles x 3 loads).
__global__ void __launch_bounds__(512, 2)
g2_kernel(const ushort* __restrict__ H, const ushort* __restrict__ W2,
          const float* __restrict__ sb2, float* __restrict__ out,
          ushort* __restrict__ y2, const int* __restrict__ ctrl)
{
    __shared__ ushort lds[49152];   // 96 KB: 4 bufs x (8192 A + 4096 B)
    int bx, col0;
    xcd_remap(bx, col0);
    if (bx >= ctrl[0]) return;
    const int e     = ctrl[32 + 2*bx];
    const int slot0 = ctrl[32 + 2*bx + 1];
    const int sbase = ctrl[2];
    const int tt = threadIdx.x;
    const int lane = tt & 63, wid = tt >> 6;
    const int wm = wid >> 1, wn = wid & 1;
    const int wofs = wid * 512;

    const int slog = (tt & 7) ^ ((tt >> 3) & 7);
    const int kk0 = (slog & 3) * 8;
    const int r0 = ((tt >> 3) << 1) + (slog >> 2);
    const ushort* pA0 = H + (size_t)(slot0 + r0) * DIM + kk0;
    const ushort* pA1 = H + (size_t)(slot0 + r0 + 128) * DIM + kk0;
    const ushort* Be  = W2 + (size_t)e * (DIM*DIM);
    const ushort* pB1 = Be + (size_t)(col0 + r0) * DIM + kk0;

    const int hi = lane >> 4, lr = lane & 15;
    int aoff[4], boff[4];
#pragma unroll
    for (int m = 0; m < 4; m++) {
        int row = wm*64 + m*16 + lr;
        int lrow = row >> 1;
        int sl = ((row & 1) << 2) | hi;
        aoff[m] = lrow*64 + (sl ^ (lrow & 7))*8;
    }
#pragma unroll
    for (int n = 0; n < 4; n++) {
        int oc = wn*64 + n*16 + lr;
        int lrow = oc >> 1;
        int sl = ((oc & 1) << 2) | hi;
        boff[n] = lrow*64 + (sl ^ (lrow & 7))*8;
    }

    f32x4 zero4 = {0.f, 0.f, 0.f, 0.f};
    f32x4 acc[4][4];
#pragma unroll
    for (int m = 0; m < 4; m++)
#pragma unroll
        for (int n = 0; n < 4; n++) acc[m][n] = zero4;

    auto stage = [&](int buf, int kte) {
        ushort* b = &lds[buf * 12288];
        gll16(pA0 + kte, b + wofs);
        gll16(pA1 + kte, b + 4096 + wofs);
        gll16(pB1 + kte, b + 8192 + wofs);
    };
    auto compute = [&](int buf) {
        const ushort* Ab = &lds[buf * 12288];
        const ushort* Bb = Ab + 8192;
        bf16x8 a[4], bv[4];
#pragma unroll
        for (int m = 0; m < 4; m++) a[m] = *(const bf16x8*)(Ab + aoff[m]);
#pragma unroll
        for (int n = 0; n < 4; n++) bv[n] = *(const bf16x8*)(Bb + boff[n]);
        __builtin_amdgcn_s_setprio(1);
#pragma unroll
        for (int m = 0; m < 4; m++)
#pragma unroll
            for (int n = 0; n < 4; n++)
                acc[m][n] = __builtin_amdgcn_mfma_f32_16x16x32_bf16(a[m], bv[n], acc[m][n], 0, 0, 0);
        __builtin_amdgcn_s_setprio(0);
    };

    stage(0, 0); stage(1, 32); stage(2, 64);
    asm volatile("s_waitcnt vmcnt(6)" ::: "memory");      // tile 0 landed
    __builtin_amdgcn_s_barrier();
    asm volatile("" ::: "memory");
    for (int t = 0; t < 29; ++t) {
        stage((t + 3) & 3, (t + 3) * 32);
        compute(t & 3);
        asm volatile("s_waitcnt vmcnt(6)" ::: "memory");  // t+1 landed; 2 tiles in flight
        __builtin_amdgcn_s_barrier();
        asm volatile("" ::: "memory");
    }
    compute(1);                                           // tile 29
    asm volatile("s_waitcnt vmcnt(3)" ::: "memory");      // tile 30 landed
    __builtin_amdgcn_s_barrier();
    asm volatile("" ::: "memory");
    compute(2);                                           // tile 30
    asm volatile("s_waitcnt vmcnt(0)" ::: "memory");      // tile 31 landed
    __builtin_amdgcn_s_barrier();
    asm volatile("" ::: "memory");
    compute(3);                                           // tile 31

#pragma unroll
    for (int m = 0; m < 4; m++)
#pragma unroll
        for (int n = 0; n < 4; n++)
#pragma unroll
            for (int r = 0; r < 4; r++) {
                int row = slot0 + wm*64 + m*16 + hi*4 + r;
                int col = col0 + wn*64 + n*16 + lr;
                float v = acc[m][n][r];
                if (e != NE) y2[(size_t)row * DIM + col] = f2bf(v);
                else         out[(size_t)(row - sbase) * DIM + col] = v + sb2[col];
            }
}

// --------- combine: out[n] += sum_k w_k * y2[slot_k(n)] ----------------------
__global__ void __launch_bounds__(256)
combine_kernel(const ushort* __restrict__ y2, const int* __restrict__ slots,
               const float* __restrict__ topk_w, float* __restrict__ out)
{
    __shared__ int ss[3];
    __shared__ float sw[3];
    const int n = blockIdx.x, tid = threadIdx.x;
    if (tid < 3) { ss[tid] = slots[n * 3 + tid]; sw[tid] = topk_w[n * 3 + tid]; }
    __syncthreads();
    float4* o4 = (float4*)(out + (size_t)n * DIM);
    float4 o = o4[tid];
#pragma unroll
    for (int k = 0; k < 3; k++) {
        const ushort4 yv = *(const ushort4*)(y2 + (size_t)ss[k] * DIM + tid * 4);
        float w = sw[k];
        o.x += w * bf2f(yv.x);
        o.y += w * bf2f(yv.y);
        o.z += w * bf2f(yv.z);
        o.w += w * bf2f(yv.w);
    }
    o4[tid] = o;
}

extern "C" void kernel_launch(void* const* d_in, const int* in_sizes, int n_in,
                              void* d_out, int out_size, void* d_ws, size_t ws_size,
                              hipStream_t stream)
{
    const float* x    = (const float*)d_in[0];
    const float* gw   = (const float*)d_in[1];
    const float* gb   = (const float*)d_in[2];
    const float* bia  = (const float*)d_in[3];
    const float* w1   = (const float*)d_in[4];
    const float* wg   = (const float*)d_in[5];
    const float* w2   = (const float*)d_in[6];
    const float* sw1  = (const float*)d_in[7];
    const float* sb1  = (const float*)d_in[8];
    const float* sw2  = (const float*)d_in[9];
    const float* sb2  = (const float*)d_in[10];
    float* out = (float*)d_out;

    // Workspace layout (bytes); total 173,452,288 <= proven ws_size >= 186,625,024.
    char* ws = (char*)d_ws;
    int*    ctrl   = (int*)   (ws + 0);          // [0]=ntiles [1]=rows [2]=shared_base, +8 counts, +16 cursors, +32 tiles
    int*    topk_e = (int*)   (ws + 4096);       //  98,304
    float*  topk_w = (float*) (ws + 102400);     //  98,304
    int*    slots  = (int*)   (ws + 200704);     //  98,304
    int*    row_tok= (int*)   (ws + 299008);     // 138,240 (34560 ints) -> pad to 437,248
    ushort* w1T    = (ushort*)(ws + 437248);     // 8 x 2MB (e7 = sw1T)
    ushort* wgT    = (ushort*)(ws + 17214464);   // 7 x 2MB
    ushort* w2T    = (ushort*)(ws + 31894528);   // 8 x 2MB (e7 = sw2T)
    ushort* h1     = (ushort*)(ws + 48671744);   // 34560 x 1024 bf16 = 70,778,880
    ushort* y2     = (ushort*)(ws + 119450624);  // 26368 x 1024 bf16 = 54,001,664 -> end 173,452,288
    ushort* xb     = y2;                         // alias: xb dead before g2 writes y2

    hipMemsetAsync(ctrl, 0, 4096, stream);
    hipMemsetAsync(row_tok, 0, 34560 * 4, stream);   // pad slots default to token 0
    transpose_convert<<<dim3(32, 32, 23), 256, 0, stream>>>(w1, wg, w2, sw1, sw2,
                                                            w1T, wgT, w2T);
    gate_kernel<<<N_TOK / 16, 256, 0, stream>>>(x, gw, gb, bia, topk_e, topk_w,
                                                ctrl + 8, xb);
    setup_kernel<<<1, 64, 0, stream>>>(ctrl);
    ident_kernel<<<N_TOK / 256, 256, 0, stream>>>(ctrl, row_tok);
    scatter_kernel<<<N_TOK / 256, 256, 0, stream>>>(topk_e, topk_w, ctrl, row_tok,
                                                    slots);

    g1_kernel<<<dim3(MT_TILES, 8), 512, 0, stream>>>(xb, w1T, wgT, sb1, h1,
                                                     row_tok, ctrl);
    g2_kernel<<<dim3(MT_TILES, 8), 512, 0, stream>>>(h1, w2T, sb2, out, y2, ctrl);
    combine_kernel<<<N_TOK, 256, 0, stream>>>(y2, slots, topk_w, out);
}

// Round 9
// 466.674 us; speedup vs baseline: 2.0959x; 1.0145x over previous
//
#include <hip/hip_runtime.h>
#include <hip/hip_bf16.h>

// DeepSeekMoE: B=4,S=2048,D=1024,H=1024,E=7,NS=1,topk=3. N=8192 tokens.
#define N_TOK 8192
#define DIM   1024
#define NE    7
#define MT_TILES 136   // <= ~103 routed tiles + 32 shared + slack; 136*8 % 8 == 0

typedef __attribute__((ext_vector_type(8))) short bf16x8;
typedef __attribute__((ext_vector_type(4))) float f32x4;

typedef __attribute__((address_space(3))) ushort lds_us_t;
typedef __attribute__((address_space(1))) const ushort glb_us_t;

__device__ __forceinline__ void gll16(const ushort* g, ushort* l) {
    __builtin_amdgcn_global_load_lds((glb_us_t*)g, (lds_us_t*)l, 16, 0, 0);
}

__device__ __forceinline__ unsigned short f2bf(float f) {
    unsigned int u = __builtin_bit_cast(unsigned int, f);
    u += 0x7fffu + ((u >> 16) & 1u);   // RNE
    return (unsigned short)(u >> 16);
}

__device__ __forceinline__ float bf2f(unsigned short b) {
    unsigned int u = ((unsigned int)b) << 16;
    return __builtin_bit_cast(float, u);
}

__device__ __forceinline__ float siluf(float v) { return v / (1.f + __expf(-v)); }

// ---------------- gate: logits -> softmax -> top3 -> renorm weights ----------
// Fuses x fp32->bf16 conversion.
__global__ void __launch_bounds__(256)
gate_kernel(const float* __restrict__ x, const float* __restrict__ gw,
            const float* __restrict__ gb, const float* __restrict__ bia,
            int* __restrict__ topk_e, float* __restrict__ topk_w,
            int* __restrict__ counts, ushort* __restrict__ xb)
{
    __shared__ float gwT[NE][DIM];   // 28 KB
    __shared__ int cnt[NE];
    const int tid = threadIdx.x;
    if (tid < NE) cnt[tid] = 0;
    for (int t = tid; t < NE * DIM; t += 256) {
        int d = t / NE, e = t - d * NE;
        gwT[e][d] = gw[t];
    }
    __syncthreads();

    const int lane = tid & 63, wid = tid >> 6;
#pragma unroll
    for (int tt = 0; tt < 4; tt++) {
        const int n = blockIdx.x * 16 + wid * 4 + tt;
        const float4* xr = (const float4*)(x + (size_t)n * DIM);
        ushort4* xo = (ushort4*)(xb + (size_t)n * DIM);
        float p[NE];
#pragma unroll
        for (int e = 0; e < NE; e++) p[e] = 0.f;
#pragma unroll
        for (int it = 0; it < 4; it++) {
            int i4 = it * 64 + lane;
            float4 v = xr[i4];
            ushort4 o;
            o.x = f2bf(v.x); o.y = f2bf(v.y); o.z = f2bf(v.z); o.w = f2bf(v.w);
            xo[i4] = o;
            int d = i4 * 4;
#pragma unroll
            for (int e = 0; e < NE; e++) {
                float4 g = *(const float4*)&gwT[e][d];
                p[e] += v.x * g.x + v.y * g.y + v.z * g.z + v.w * g.w;
            }
        }
#pragma unroll
        for (int e = 0; e < NE; e++)
            for (int off = 32; off; off >>= 1) p[e] += __shfl_xor(p[e], off);
        if (lane == 0) {
            float l[NE], m = -1e30f;
#pragma unroll
            for (int e = 0; e < NE; e++) { l[e] = p[e] + gb[e]; m = fmaxf(m, l[e]); }
            float s = 0.f;
#pragma unroll
            for (int e = 0; e < NE; e++) { l[e] = __expf(l[e] - m); s += l[e]; }
            float inv = 1.f / s;
#pragma unroll
            for (int e = 0; e < NE; e++) l[e] *= inv;          // probs
            float adj[NE]; bool used[NE];
#pragma unroll
            for (int e = 0; e < NE; e++) { adj[e] = l[e] + bia[e]; used[e] = false; }
            int sel[3]; float w[3]; float ws = 0.f;
            for (int k = 0; k < 3; k++) {
                int b = -1; float bv = -1e30f;
                for (int e = 0; e < NE; e++)
                    if (!used[e] && adj[e] > bv) { bv = adj[e]; b = e; }
                used[b] = true; sel[k] = b; w[k] = l[b]; ws += w[k];
            }
            float iws = 1.f / ws;
            for (int k = 0; k < 3; k++) {
                topk_e[n * 3 + k] = sel[k];
                topk_w[n * 3 + k] = w[k] * iws;
                atomicAdd(&cnt[sel[k]], 1);
            }
        }
    }
    __syncthreads();
    if (tid < NE) atomicAdd(&counts[tid], cnt[tid]);
}

// --------- setup (1 thread): 256-pad scan + tile list (pads memset'd) --------
__global__ void setup_kernel(int* __restrict__ ctrl)
{
    if (threadIdx.x != 0 || blockIdx.x != 0) return;
    int* counts = ctrl + 8; int* cursors = ctrl + 16; int* tiles = ctrl + 32;
    int nm = 0, off = 0;
    for (int e = 0; e < NE; e++) {
        int c = counts[e];
        int padc = (c + 255) & ~255;
        cursors[e] = off;
        for (int t = 0; t < padc; t += 256) { tiles[nm*2] = e; tiles[nm*2+1] = off + t; nm++; }
        off += padc;
    }
    ctrl[2] = off;                       // shared_base
    for (int t = 0; t < N_TOK; t += 256) { tiles[nm*2] = NE; tiles[nm*2+1] = off + t; nm++; }
    ctrl[1] = off + N_TOK;               // total rows
    ctrl[0] = nm;                        // tile count
}

// --------- identity fill for shared region -----------------------------------
__global__ void ident_kernel(const int* __restrict__ ctrl, int* __restrict__ row_tok)
{
    int n = blockIdx.x * 256 + threadIdx.x;
    row_tok[ctrl[2] + n] = n;
}

// --------- scatter: token -> per-expert padded slots (+ inverse map) ---------
__global__ void scatter_kernel(const int* __restrict__ topk_e, const float* __restrict__ topk_w,
                               int* __restrict__ ctrl, int* __restrict__ row_tok,
                               int* __restrict__ slots)
{
    int n = blockIdx.x * blockDim.x + threadIdx.x;
    if (n >= N_TOK) return;
    int* cursors = ctrl + 16;
    for (int k = 0; k < 3; k++) {
        int e = topk_e[n * 3 + k];
        int slot = atomicAdd(&cursors[e], 1);
        row_tok[slot] = n;
        slots[n * 3 + k] = slot;
    }
}

// --------- transpose+convert weights to B^T bf16 -----------------------------
__global__ void transpose_convert(const float* __restrict__ w1, const float* __restrict__ wg,
                                  const float* __restrict__ w2, const float* __restrict__ sw1,
                                  const float* __restrict__ sw2,
                                  ushort* __restrict__ w1T, ushort* __restrict__ wgT,
                                  ushort* __restrict__ w2T)
{
    int z = blockIdx.z;
    const float* src; ushort* dst;
    if (z < 7)       { src = w1 + (size_t)z * (DIM*DIM);        dst = w1T + (size_t)z * (DIM*DIM); }
    else if (z < 14) { src = wg + (size_t)(z - 7) * (DIM*DIM);  dst = wgT + (size_t)(z - 7) * (DIM*DIM); }
    else if (z < 21) { src = w2 + (size_t)(z - 14) * (DIM*DIM); dst = w2T + (size_t)(z - 14) * (DIM*DIM); }
    else if (z == 21){ src = sw1; dst = w1T + (size_t)NE * (DIM*DIM); }
    else             { src = sw2; dst = w2T + (size_t)NE * (DIM*DIM); }
    __shared__ float t[32][33];
    int bx = blockIdx.x * 32, by = blockIdx.y * 32;
    int lx = threadIdx.x & 31, ly = threadIdx.x >> 5;
#pragma unroll
    for (int i = 0; i < 32; i += 8)
        t[ly + i][lx] = src[(size_t)(by + ly + i) * DIM + bx + lx];
    __syncthreads();
#pragma unroll
    for (int i = 0; i < 32; i += 8) {
        int r = ly + i;
        dst[(size_t)(bx + r) * DIM + by + lx] = f2bf(t[lx][r]);
    }
}

// XCD-aware remap: XCD k owns x-tiles [17k,17k+17) x all 8 col-blocks.
__device__ __forceinline__ void xcd_remap(int& bx, int& col0) {
    int L = blockIdx.x + blockIdx.y * MT_TILES;
    int D = (L & 7) * MT_TILES + (L >> 3);
    bx = D >> 3;
    col0 = (D & 7) * 128;
}

// ============ GEMM: BM=256 BN=128 BK=32, double-buffer, 2 blocks/CU ==========
// Dual-row packed LDS swizzle (2 lanes/bank, free); gll16 linear dest with
// inverse-swizzled global source (rule #21). 64 KB LDS (g1) / 48 KB (g2) so
// TWO blocks co-reside per CU: the vmcnt(0)+barrier drain of one block is
// hidden by the sibling block's compute (m97/m114 recipe).

// ---- G1: h = silu(x@w1)*(x@wg)  (e<7)  |  silu(x@sw1 + sb1)  (e==7) ---------
__global__ void __launch_bounds__(512, 2)
g1_kernel(const ushort* __restrict__ Xb, const ushort* __restrict__ W1,
          const ushort* __restrict__ WG, const float* __restrict__ sb1,
          ushort* __restrict__ H, const int* __restrict__ row_tok,
          const int* __restrict__ ctrl)
{
    __shared__ ushort lds[32768];   // 64 KB: 2 bufs x (8192 A + 4096 B1 + 4096 B2)
    int bx, col0;
    xcd_remap(bx, col0);
    if (bx >= ctrl[0]) return;
    const int e     = ctrl[32 + 2*bx];
    const int slot0 = ctrl[32 + 2*bx + 1];
    const bool gated = (e != NE);
    const int tt = threadIdx.x;
    const int lane = tt & 63, wid = tt >> 6;
    const int wm = wid >> 1, wn = wid & 1;
    const int wofs = wid * 512;

    // staging source (inverse-swizzled global address)
    const int slog = (tt & 7) ^ ((tt >> 3) & 7);
    const int kk0 = (slog & 3) * 8;
    const int r0 = ((tt >> 3) << 1) + (slog >> 2);
    const ushort* pA0 = Xb + (size_t)row_tok[slot0 + r0] * DIM + kk0;
    const ushort* pA1 = Xb + (size_t)row_tok[slot0 + r0 + 128] * DIM + kk0;
    const ushort* B1e = W1 + (size_t)e * (DIM*DIM);
    const ushort* B2e = gated ? (WG + (size_t)e * (DIM*DIM))
                              : (W1 + (size_t)NE * (DIM*DIM));
    const ushort* pB1 = B1e + (size_t)(col0 + r0) * DIM + kk0;
    const ushort* pB2 = B2e + (size_t)(col0 + r0) * DIM + kk0;

    // fragment read offsets (swizzled)
    const int hi = lane >> 4, lr = lane & 15;
    int aoff[4], boff[4];
#pragma unroll
    for (int m = 0; m < 4; m++) {
        int row = wm*64 + m*16 + lr;
        int lrow = row >> 1;
        int sl = ((row & 1) << 2) | hi;
        aoff[m] = lrow*64 + (sl ^ (lrow & 7))*8;
    }
#pragma unroll
    for (int n = 0; n < 4; n++) {
        int oc = wn*64 + n*16 + lr;
        int lrow = oc >> 1;
        int sl = ((oc & 1) << 2) | hi;
        boff[n] = lrow*64 + (sl ^ (lrow & 7))*8;
    }

    f32x4 zero4 = {0.f, 0.f, 0.f, 0.f};
    f32x4 acc1[4][4], acc2[4][4];
#pragma unroll
    for (int m = 0; m < 4; m++)
#pragma unroll
        for (int n = 0; n < 4; n++) { acc1[m][n] = zero4; acc2[m][n] = zero4; }

    auto stage = [&](int buf, int kte) {
        ushort* b = &lds[buf * 16384];
        gll16(pA0 + kte, b + wofs);
        gll16(pA1 + kte, b + 4096 + wofs);
        gll16(pB1 + kte, b + 8192 + wofs);
        gll16(pB2 + kte, b + 12288 + wofs);
    };
    auto compute = [&](int buf) {
        const ushort* Ab = &lds[buf * 16384];
        const ushort* Bb = Ab + 8192;
        bf16x8 a[4], bv[4];
#pragma unroll
        for (int m = 0; m < 4; m++) a[m] = *(const bf16x8*)(Ab + aoff[m]);
#pragma unroll
        for (int n = 0; n < 4; n++) bv[n] = *(const bf16x8*)(Bb + boff[n]);
        __builtin_amdgcn_s_setprio(1);
#pragma unroll
        for (int m = 0; m < 4; m++)
#pragma unroll
            for (int n = 0; n < 4; n++)
                acc1[m][n] = __builtin_amdgcn_mfma_f32_16x16x32_bf16(a[m], bv[n], acc1[m][n], 0, 0, 0);
        __builtin_amdgcn_s_setprio(0);
        if (gated) {
            const ushort* B2b = Ab + 12288;
            bf16x8 b2[4];
#pragma unroll
            for (int n = 0; n < 4; n++) b2[n] = *(const bf16x8*)(B2b + boff[n]);
            __builtin_amdgcn_s_setprio(1);
#pragma unroll
            for (int m = 0; m < 4; m++)
#pragma unroll
                for (int n = 0; n < 4; n++)
                    acc2[m][n] = __builtin_amdgcn_mfma_f32_16x16x32_bf16(a[m], b2[n], acc2[m][n], 0, 0, 0);
            __builtin_amdgcn_s_setprio(0);
        }
    };

    // double-buffer: stage t+1 during t; drain before swap (sibling block hides it)
    stage(0, 0);
    asm volatile("s_waitcnt vmcnt(0)" ::: "memory");
    __builtin_amdgcn_s_barrier();
    asm volatile("" ::: "memory");
    for (int t = 0; t < 31; ++t) {
        stage((t + 1) & 1, (t + 1) * 32);
        compute(t & 1);
        asm volatile("s_waitcnt vmcnt(0)" ::: "memory");
        __builtin_amdgcn_s_barrier();
        asm volatile("" ::: "memory");
    }
    compute(1);                                           // tile 31

    // epilogue: SwiGLU (routed) / bias-silu (shared)
#pragma unroll
    for (int m = 0; m < 4; m++)
#pragma unroll
        for (int n = 0; n < 4; n++)
#pragma unroll
            for (int r = 0; r < 4; r++) {
                int row = slot0 + wm*64 + m*16 + hi*4 + r;
                int col = col0 + wn*64 + n*16 + lr;
                float v1 = acc1[m][n][r];
                float h = gated ? siluf(v1) * acc2[m][n][r]
                                : siluf(v1 + sb1[col]);
                H[(size_t)row * DIM + col] = f2bf(h);
            }
}

// ---- G2: y = h @ w2 ; routed -> y2 bf16 ; shared -> out = y + sb2 (fp32) ----
// Double-buffer (48 KB LDS) -> 2 blocks/CU.
__global__ void __launch_bounds__(512, 2)
g2_kernel(const ushort* __restrict__ H, const ushort* __restrict__ W2,
          const float* __restrict__ sb2, float* __restrict__ out,
          ushort* __restrict__ y2, const int* __restrict__ ctrl)
{
    __shared__ ushort lds[24576];   // 48 KB: 2 bufs x (8192 A + 4096 B)
    int bx, col0;
    xcd_remap(bx, col0);
    if (bx >= ctrl[0]) return;
    const int e     = ctrl[32 + 2*bx];
    const int slot0 = ctrl[32 + 2*bx + 1];
    const int sbase = ctrl[2];
    const int tt = threadIdx.x;
    const int lane = tt & 63, wid = tt >> 6;
    const int wm = wid >> 1, wn = wid & 1;
    const int wofs = wid * 512;

    const int slog = (tt & 7) ^ ((tt >> 3) & 7);
    const int kk0 = (slog & 3) * 8;
    const int r0 = ((tt >> 3) << 1) + (slog >> 2);
    const ushort* pA0 = H + (size_t)(slot0 + r0) * DIM + kk0;
    const ushort* pA1 = H + (size_t)(slot0 + r0 + 128) * DIM + kk0;
    const ushort* Be  = W2 + (size_t)e * (DIM*DIM);
    const ushort* pB1 = Be + (size_t)(col0 + r0) * DIM + kk0;

    const int hi = lane >> 4, lr = lane & 15;
    int aoff[4], boff[4];
#pragma unroll
    for (int m = 0; m < 4; m++) {
        int row = wm*64 + m*16 + lr;
        int lrow = row >> 1;
        int sl = ((row & 1) << 2) | hi;
        aoff[m] = lrow*64 + (sl ^ (lrow & 7))*8;
    }
#pragma unroll
    for (int n = 0; n < 4; n++) {
        int oc = wn*64 + n*16 + lr;
        int lrow = oc >> 1;
        int sl = ((oc & 1) << 2) | hi;
        boff[n] = lrow*64 + (sl ^ (lrow & 7))*8;
    }

    f32x4 zero4 = {0.f, 0.f, 0.f, 0.f};
    f32x4 acc[4][4];
#pragma unroll
    for (int m = 0; m < 4; m++)
#pragma unroll
        for (int n = 0; n < 4; n++) acc[m][n] = zero4;

    auto stage = [&](int buf, int kte) {
        ushort* b = &lds[buf * 12288];
        gll16(pA0 + kte, b + wofs);
        gll16(pA1 + kte, b + 4096 + wofs);
        gll16(pB1 + kte, b + 8192 + wofs);
    };
    auto compute = [&](int buf) {
        const ushort* Ab = &lds[buf * 12288];
        const ushort* Bb = Ab + 8192;
        bf16x8 a[4], bv[4];
#pragma unroll
        for (int m = 0; m < 4; m++) a[m] = *(const bf16x8*)(Ab + aoff[m]);
#pragma unroll
        for (int n = 0; n < 4; n++) bv[n] = *(const bf16x8*)(Bb + boff[n]);
        __builtin_amdgcn_s_setprio(1);
#pragma unroll
        for (int m = 0; m < 4; m++)
#pragma unroll
            for (int n = 0; n < 4; n++)
                acc[m][n] = __builtin_amdgcn_mfma_f32_16x16x32_bf16(a[m], bv[n], acc[m][n], 0, 0, 0);
        __builtin_amdgcn_s_setprio(0);
    };

    stage(0, 0);
    asm volatile("s_waitcnt vmcnt(0)" ::: "memory");
    __builtin_amdgcn_s_barrier();
    asm volatile("" ::: "memory");
    for (int t = 0; t < 31; ++t) {
        stage((t + 1) & 1, (t + 1) * 32);
        compute(t & 1);
        asm volatile("s_waitcnt vmcnt(0)" ::: "memory");
        __builtin_amdgcn_s_barrier();
        asm volatile("" ::: "memory");
    }
    compute(1);                                           // tile 31

#pragma unroll
    for (int m = 0; m < 4; m++)
#pragma unroll
        for (int n = 0; n < 4; n++)
#pragma unroll
            for (int r = 0; r < 4; r++) {
                int row = slot0 + wm*64 + m*16 + hi*4 + r;
                int col = col0 + wn*64 + n*16 + lr;
                float v = acc[m][n][r];
                if (e != NE) y2[(size_t)row * DIM + col] = f2bf(v);
                else         out[(size_t)(row - sbase) * DIM + col] = v + sb2[col];
            }
}

// --------- combine: out[n] += sum_k w_k * y2[slot_k(n)] ----------------------
__global__ void __launch_bounds__(256)
combine_kernel(const ushort* __restrict__ y2, const int* __restrict__ slots,
               const float* __restrict__ topk_w, float* __restrict__ out)
{
    __shared__ int ss[3];
    __shared__ float sw[3];
    const int n = blockIdx.x, tid = threadIdx.x;
    if (tid < 3) { ss[tid] = slots[n * 3 + tid]; sw[tid] = topk_w[n * 3 + tid]; }
    __syncthreads();
    float4* o4 = (float4*)(out + (size_t)n * DIM);
    float4 o = o4[tid];
#pragma unroll
    for (int k = 0; k < 3; k++) {
        const ushort4 yv = *(const ushort4*)(y2 + (size_t)ss[k] * DIM + tid * 4);
        float w = sw[k];
        o.x += w * bf2f(yv.x);
        o.y += w * bf2f(yv.y);
        o.z += w * bf2f(yv.z);
        o.w += w * bf2f(yv.w);
    }
    o4[tid] = o;
}

extern "C" void kernel_launch(void* const* d_in, const int* in_sizes, int n_in,
                              void* d_out, int out_size, void* d_ws, size_t ws_size,
                              hipStream_t stream)
{
    const float* x    = (const float*)d_in[0];
    const float* gw   = (const float*)d_in[1];
    const float* gb   = (const float*)d_in[2];
    const float* bia  = (const float*)d_in[3];
    const float* w1   = (const float*)d_in[4];
    const float* wg   = (const float*)d_in[5];
    const float* w2   = (const float*)d_in[6];
    const float* sw1  = (const float*)d_in[7];
    const float* sb1  = (const float*)d_in[8];
    const float* sw2  = (const float*)d_in[9];
    const float* sb2  = (const float*)d_in[10];
    float* out = (float*)d_out;

    // Workspace layout (bytes); total 173,452,288 <= proven ws_size >= 186,625,024.
    char* ws = (char*)d_ws;
    int*    ctrl   = (int*)   (ws + 0);          // [0]=ntiles [1]=rows [2]=shared_base, +8 counts, +16 cursors, +32 tiles
    int*    topk_e = (int*)   (ws + 4096);       //  98,304
    float*  topk_w = (float*) (ws + 102400);     //  98,304
    int*    slots  = (int*)   (ws + 200704);     //  98,304
    int*    row_tok= (int*)   (ws + 299008);     // 138,240 (34560 ints) -> pad to 437,248
    ushort* w1T    = (ushort*)(ws + 437248);     // 8 x 2MB (e7 = sw1T)
    ushort* wgT    = (ushort*)(ws + 17214464);   // 7 x 2MB
    ushort* w2T    = (ushort*)(ws + 31894528);   // 8 x 2MB (e7 = sw2T)
    ushort* h1     = (ushort*)(ws + 48671744);   // 34560 x 1024 bf16 = 70,778,880
    ushort* y2     = (ushort*)(ws + 119450624);  // 26368 x 1024 bf16 = 54,001,664 -> end 173,452,288
    ushort* xb     = y2;                         // alias: xb dead before g2 writes y2

    hipMemsetAsync(ctrl, 0, 4096, stream);
    hipMemsetAsync(row_tok, 0, 34560 * 4, stream);   // pad slots default to token 0
    transpose_convert<<<dim3(32, 32, 23), 256, 0, stream>>>(w1, wg, w2, sw1, sw2,
                                                            w1T, wgT, w2T);
    gate_kernel<<<N_TOK / 16, 256, 0, stream>>>(x, gw, gb, bia, topk_e, topk_w,
                                                ctrl + 8, xb);
    setup_kernel<<<1, 64, 0, stream>>>(ctrl);
    ident_kernel<<<N_TOK / 256, 256, 0, stream>>>(ctrl, row_tok);
    scatter_kernel<<<N_TOK / 256, 256, 0, stream>>>(topk_e, topk_w, ctrl, row_tok,
                                                    slots);

    g1_kernel<<<dim3(MT_TILES, 8), 512, 0, stream>>>(xb, w1T, wgT, sb1, h1,
                                                     row_tok, ctrl);
    g2_kernel<<<dim3(MT_TILES, 8), 512, 0, stream>>>(h1, w2T, sb2, out, y2, ctrl);
    combine_kernel<<<N_TOK, 256, 0, stream>>>(y2, slots, topk_w, out);
}